// Round 22
// baseline (343.499 us; speedup 1.0000x reference)
//
#include <hip/hip_runtime.h>

// ---- problem constants (match reference) ----
namespace {
constexpr int NN   = 100000;  // nodes
constexpr int RR   = 3;       // relations
constexpr int EE   = 500000;  // edges per relation
constexpr int FIN  = 256;
constexpr int FHID = 128;
constexpr int FOUT = 64;
constexpr int EEC  = RR * EE;                         // combined edges
constexpr int SCAN_TILE = 4096;                       // elems per scan block
constexpr int NB = (NN + SCAN_TILE - 1) / SCAN_TILE;  // 25 blocks (combined scan)
// histogram geometry (counts fit ushort: per-slice per-node deg <= SLICE < 65536)
constexpr int NCHUNK  = 8;                 // hist chunks (12500 nodes, 50 KB LDS)
constexpr int CH      = NN / NCHUNK;
constexpr int GH      = 50;                // edge slices; SLICE*4B is 16B-aligned
constexpr int SLICE   = EE / GH;           // 10000
// fill geometry (6250-node chunks, 25 KB LDS)
constexpr int NCHUNK_F = 16;
constexpr int CH_F     = NN / NCHUNK_F;    // 6250
constexpr int FILL_BLOCKS = NCHUNK_F * GH; // 800
}

typedef float f32x4  __attribute__((ext_vector_type(4)));
typedef short bf16x8 __attribute__((ext_vector_type(8)));

__device__ inline unsigned bf16round(float a) {
    unsigned u = __float_as_uint(a);
    return (u + 0x7FFFu + ((u >> 16) & 1u)) >> 16;   // RNE
}
__device__ inline unsigned pack2_bf16(float a, float b) {
    return bf16round(a) | (bf16round(b) << 16);
}
__device__ inline float bflo(unsigned u) { return __uint_as_float(u << 16); }
__device__ inline float bfhi(unsigned u) { return __uint_as_float(u & 0xFFFF0000u); }

// async global->LDS 16B copy (linear dest: wave base + lane*16)
__device__ inline void gload_lds16(const unsigned short* g, unsigned short* l) {
    __builtin_amdgcn_global_load_lds(
        (const __attribute__((address_space(1))) void*)g,
        (__attribute__((address_space(3))) void*)l, 16, 0, 0);
}

// ---------------- fused weight transpose+convert: Wt[r][m][k] = bf16(W[r][k][m]) ----
__global__ __launch_bounds__(256) void convw_kernel(
    const float* __restrict__ W1, unsigned short* __restrict__ Wt1,
    const float* __restrict__ W2, unsigned short* __restrict__ Wt2)
{
    int idx = blockIdx.x * 256 + threadIdx.x;
    const int n1 = RR * FIN * FHID;
    const int n2 = RR * FHID * FOUT;
    if (idx < n1) {
        int r = idx / (FIN * FHID);
        int rem = idx - r * FIN * FHID;
        int k = rem / FHID, m = rem - k * FHID;
        Wt1[((size_t)r * FHID + m) * FIN + k] = (unsigned short)bf16round(W1[idx]);
    } else if (idx - n1 < n2) {
        int j = idx - n1;
        int r = j / (FHID * FOUT);
        int rem = j - r * FHID * FOUT;
        int k = rem / FOUT, m = rem - k * FOUT;
        Wt2[((size_t)r * FOUT + m) * FHID + k] = (unsigned short)bf16round(W2[j]);
    }
}

// ---------------- LDS-histogram degree count (int4 edges, ushort partials) ----
__global__ __launch_bounds__(512) void hist_deg_kernel(
    const int* __restrict__ src, const int* __restrict__ dst,
    unsigned short* __restrict__ partial_in, unsigned short* __restrict__ partial_out)
{
    __shared__ int cnt[CH];   // 50 KB
    const int b   = blockIdx.x;
    const int dir = b / (RR * NCHUNK * GH);
    const int rem = b % (RR * NCHUNK * GH);
    const int r   = rem / (NCHUNK * GH);
    const int c   = (rem / GH) % NCHUNK;
    const int g   = rem % GH;
    const int tid = threadIdx.x;

    for (int i = tid; i < CH; i += 512) cnt[i] = 0;
    __syncthreads();

    const int* ids = (dir ? src : dst) + (size_t)r * EE + (size_t)g * SLICE;
    const int base = c * CH;
    for (int i4 = tid; i4 < SLICE / 4; i4 += 512) {
        int4 q = reinterpret_cast<const int4*>(ids)[i4];
        int d;
        d = q.x - base; if ((unsigned)d < (unsigned)CH) atomicAdd(&cnt[d], 1);
        d = q.y - base; if ((unsigned)d < (unsigned)CH) atomicAdd(&cnt[d], 1);
        d = q.z - base; if ((unsigned)d < (unsigned)CH) atomicAdd(&cnt[d], 1);
        d = q.w - base; if ((unsigned)d < (unsigned)CH) atomicAdd(&cnt[d], 1);
    }
    __syncthreads();

    unsigned short* part = (dir ? partial_out : partial_in)
                           + (size_t)g * RR * NN + (size_t)r * NN + base;
    for (int i = tid; i < CH; i += 512) part[i] = (unsigned short)cnt[i];
}

// reduce partials -> deg_in + s_in (dir 0) / s_out (dir 1)
__global__ __launch_bounds__(256) void reduce_deg_kernel(
    const unsigned short* __restrict__ partial_in,
    const unsigned short* __restrict__ partial_out,
    int* __restrict__ deg_in, float* __restrict__ s_in, float* __restrict__ s_out)
{
    int idx = blockIdx.x * 256 + threadIdx.x;
    if (idx >= 2 * RR * NN) return;
    int dir = idx / (RR * NN);
    int j   = idx % (RR * NN);
    const unsigned short* part = dir ? partial_out : partial_in;
    int s = 0;
    #pragma unroll
    for (int g = 0; g < GH; ++g) s += part[(size_t)g * RR * NN + j];
    float v = rsqrtf((float)max(s, 1));
    if (dir == 0) { deg_in[j] = s; s_in[j] = v; }
    else          { s_out[j] = v; }
}

// ---------------- scan over COMBINED degrees -> rp_c ----------------
__global__ __launch_bounds__(1024) void scan_reduce_kernel(
    const int* __restrict__ deg_in, int* __restrict__ bsum)
{
    const int b = blockIdx.x;
    const int t = threadIdx.x;
    int n0 = b * SCAN_TILE + t * 4;
    int s = 0;
    if (n0 + 3 < NN) {
        int4 a = *reinterpret_cast<const int4*>(&deg_in[n0]);
        int4 bq = *reinterpret_cast<const int4*>(&deg_in[NN + n0]);
        int4 cq = *reinterpret_cast<const int4*>(&deg_in[2 * NN + n0]);
        s = a.x + a.y + a.z + a.w + bq.x + bq.y + bq.z + bq.w + cq.x + cq.y + cq.z + cq.w;
    } else {
        for (int i = 0; i < 4; ++i)
            if (n0 + i < NN)
                s += deg_in[n0 + i] + deg_in[NN + n0 + i] + deg_in[2 * NN + n0 + i];
    }
    __shared__ int sh[1024];
    sh[t] = s;
    __syncthreads();
    for (int off = 512; off > 0; off >>= 1) {
        if (t < off) sh[t] += sh[t + off];
        __syncthreads();
    }
    if (t == 0) bsum[b] = sh[0];
}

__global__ void scan_spine_kernel(int* __restrict__ bsum)
{
    if (threadIdx.x != 0 || blockIdx.x != 0) return;
    int run = 0;
    for (int i = 0; i < NB; ++i) {
        int v = bsum[i];
        bsum[i] = run;
        run += v;
    }
}

__global__ __launch_bounds__(1024) void scan_final_kernel(
    const int* __restrict__ deg_in, const int* __restrict__ bsum,
    int* __restrict__ rp_c)
{
    const int b = blockIdx.x;
    const int t = threadIdx.x;
    int n0 = b * SCAN_TILE + t * 4;
    int v[4] = {0, 0, 0, 0};
    for (int i = 0; i < 4; ++i)
        if (n0 + i < NN)
            v[i] = deg_in[n0 + i] + deg_in[NN + n0 + i] + deg_in[2 * NN + n0 + i];
    int s = v[0] + v[1] + v[2] + v[3];
    __shared__ int sh[1024];
    sh[t] = s;
    __syncthreads();
    for (int off = 1; off < 1024; off <<= 1) {
        int x = (t >= off) ? sh[t - off] : 0;
        __syncthreads();
        if (t >= off) sh[t] += x;
        __syncthreads();
    }
    int off = bsum[b] + sh[t] - s;
    for (int i = 0; i < 4; ++i) {
        if (n0 + i < NN) { rp_c[n0 + i] = off; off += v[i]; }
    }
    if (b == NB - 1 && t == 0) rp_c[NN] = EEC;
}

// ---------------- combined slice bases: base_c[g][n] ----------------
__global__ __launch_bounds__(256) void slice_off_kernel(
    const int* __restrict__ rp_c, const unsigned short* __restrict__ partial_in,
    int* __restrict__ base_c)
{
    int n = blockIdx.x * 256 + threadIdx.x;
    if (n >= NN) return;
    int base = rp_c[n];
    #pragma unroll
    for (int g = 0; g < GH; ++g) {
        base_c[(size_t)g * NN + n] = base;
        const unsigned short* p = partial_in + (size_t)g * RR * NN + n;
        base += (int)p[0] + (int)p[NN] + (int)p[2 * NN];
    }
}

// ---------------- MEGA: fill3 (blocks 0..799) + GEMM L1 (blocks 800..) -------------
// fill and the L1 GEMM are independent (both feed gather1); co-scheduling them
// overlaps fill's memory latency with GEMM's MFMA phases. LDS manually unioned.
template<int K, int CN, bool A_F32>
__global__ __launch_bounds__(256) void mega_fill_gemm_kernel(
    const int* __restrict__ src, const int* __restrict__ dst,
    const int* __restrict__ base_c, const float* __restrict__ s_in,
    uint2* __restrict__ col2,
    const void* __restrict__ Av, const unsigned short* __restrict__ Wt_base,
    const float* __restrict__ srow_base, unsigned short* __restrict__ C_base,
    int N, int gemm_gx)
{
    constexpr int BM  = 64;
    constexpr int BK  = 64;
    constexpr int MF  = 2;
    constexpr int NF  = 2;
    constexpr int LDA = A_F32 ? (BK + 8) : BK;

    __shared__ __align__(16) char smem[(size_t)BM * LDA * 2 + RR * 64 * BK * 2 + RR * BM * 4];

    const int tid = threadIdx.x;

    if ((int)blockIdx.x < FILL_BLOCKS) {
        // ---------------- fill path (256 threads) ----------------
        int* cur = (int*)smem;              // CH_F*4 = 25 KB
        const int b    = blockIdx.x;
        const int c    = b / GH;
        const int g    = b % GH;
        const int base = c * CH_F;

        const int* so = base_c + (size_t)g * NN + base;
        for (int i = tid; i < CH_F; i += 256) cur[i] = so[i];
        __syncthreads();

        for (int r = 0; r < RR; ++r) {
            const int* ds = dst + (size_t)r * EE + (size_t)g * SLICE;
            const int* ss = src + (size_t)r * EE + (size_t)g * SLICE;
            const float* si = s_in + (size_t)r * NN;
            const unsigned rbase = (unsigned)(r * NN);
            for (int i4 = tid; i4 < SLICE / 4; i4 += 256) {
                int4 d4 = reinterpret_cast<const int4*>(ds)[i4];
                int4 s4 = reinterpret_cast<const int4*>(ss)[i4];
                int dl;
                dl = d4.x - base;
                if ((unsigned)dl < (unsigned)CH_F) {
                    int pos = atomicAdd(&cur[dl], 1);
                    col2[pos] = make_uint2(rbase + (unsigned)s4.x, __float_as_uint(si[d4.x]));
                }
                dl = d4.y - base;
                if ((unsigned)dl < (unsigned)CH_F) {
                    int pos = atomicAdd(&cur[dl], 1);
                    col2[pos] = make_uint2(rbase + (unsigned)s4.y, __float_as_uint(si[d4.y]));
                }
                dl = d4.z - base;
                if ((unsigned)dl < (unsigned)CH_F) {
                    int pos = atomicAdd(&cur[dl], 1);
                    col2[pos] = make_uint2(rbase + (unsigned)s4.z, __float_as_uint(si[d4.z]));
                }
                dl = d4.w - base;
                if ((unsigned)dl < (unsigned)CH_F) {
                    int pos = atomicAdd(&cur[dl], 1);
                    col2[pos] = make_uint2(rbase + (unsigned)s4.w, __float_as_uint(si[d4.w]));
                }
            }
        }
        return;
    }

    // ---------------- GEMM path (v6 structure) ----------------
    unsigned short* As  = (unsigned short*)smem;                       // BM*LDA*2
    unsigned short* Bs  = As + (size_t)BM * LDA;                       // RR*64*BK*2
    float*          sLds = (float*)(Bs + (size_t)RR * 64 * BK);        // RR*BM*4

    const int gid  = (int)blockIdx.x - FILL_BLOCKS;
    const int bx   = gid % gemm_gx;
    const int bh   = gid / gemm_gx;
    const int wave = tid >> 6;
    const int lane = tid & 63;
    const int wr   = wave >> 1;
    const int wc   = wave & 1;
    const int row0 = bx * BM;
    const int l15  = lane & 15;
    const int lq   = lane >> 4;

    for (int i = tid; i < RR * BM; i += 256) {
        int r  = i / BM;
        int rr = row0 + (i % BM);
        sLds[i] = (rr < N) ? srow_base[(size_t)r * NN + rr] : 0.f;
    }

    f32x4 acc[RR][MF][NF];
    #pragma unroll
    for (int r = 0; r < RR; ++r)
        #pragma unroll
        for (int mi = 0; mi < MF; ++mi)
            #pragma unroll
            for (int ni = 0; ni < NF; ++ni)
                #pragma unroll
                for (int q = 0; q < 4; ++q) acc[r][mi][ni][q] = 0.0f;

    for (int k0 = 0; k0 < K; k0 += BK) {
        __syncthreads();
        if constexpr (A_F32) {
            const float* A = (const float*)Av;
            #pragma unroll
            for (int i = 0; i < 2; ++i) {
                int c2  = i * 256 + tid;
                int row = c2 >> 3;
                int fc  = (c2 & 7) * 2;
                float4 v0 = make_float4(0.f, 0.f, 0.f, 0.f);
                float4 v1 = make_float4(0.f, 0.f, 0.f, 0.f);
                if (row0 + row < N) {
                    const float* Ar = A + (size_t)(row0 + row) * K + k0 + fc * 4;
                    v0 = *reinterpret_cast<const float4*>(Ar);
                    v1 = *reinterpret_cast<const float4*>(Ar + 4);
                }
                uint4 o;
                o.x = pack2_bf16(v0.x, v0.y);
                o.y = pack2_bf16(v0.z, v0.w);
                o.z = pack2_bf16(v1.x, v1.y);
                o.w = pack2_bf16(v1.z, v1.w);
                *reinterpret_cast<uint4*>(&As[row * LDA + fc * 4]) = o;
            }
        } else {
            const unsigned short* A = (const unsigned short*)Av;
            #pragma unroll
            for (int i = 0; i < 2; ++i) {
                int c   = i * 256 + tid;
                int row = c >> 3;
                int kc  = c & 7;
                int kcs = kc ^ (row & 7);
                if (row0 + row < N)
                    gload_lds16(A + (size_t)(row0 + row) * K + k0 + kcs * 8, &As[c * 8]);
            }
        }
        #pragma unroll
        for (int i = 0; i < 6; ++i) {
            int c  = i * 256 + tid;
            int r  = c >> 9;
            int cc = c & 511;
            int n  = cc >> 3;
            int kc = cc & 7;
            int kcs = kc ^ (n & 7);
            gload_lds16(Wt_base + ((size_t)r * CN + bh * 64 + n) * K + k0 + kcs * 8,
                        &Bs[(size_t)r * 64 * BK + cc * 8]);
        }
        __syncthreads();

        #pragma unroll
        for (int kk = 0; kk < BK; kk += 32) {
            const int j = kk / 8 + lq;
            bf16x8 af[MF];
            #pragma unroll
            for (int mi = 0; mi < MF; ++mi) {
                int row = wr * 32 + mi * 16 + l15;
                if constexpr (A_F32)
                    af[mi] = *reinterpret_cast<const bf16x8*>(&As[row * LDA + kk + lq * 8]);
                else
                    af[mi] = *reinterpret_cast<const bf16x8*>(&As[row * BK + (j ^ (row & 7)) * 8]);
            }
            #pragma unroll
            for (int r = 0; r < RR; ++r) {
                bf16x8 bfg[NF];
                #pragma unroll
                for (int ni = 0; ni < NF; ++ni) {
                    int n = wc * 32 + ni * 16 + l15;
                    bfg[ni] = *reinterpret_cast<const bf16x8*>(
                        &Bs[(size_t)r * 64 * BK + n * BK + (j ^ (n & 7)) * 8]);
                }
                #pragma unroll
                for (int mi = 0; mi < MF; ++mi)
                    #pragma unroll
                    for (int ni = 0; ni < NF; ++ni)
                        acc[r][mi][ni] = __builtin_amdgcn_mfma_f32_16x16x32_bf16(
                            af[mi], bfg[ni], acc[r][mi][ni], 0, 0, 0);
            }
        }
    }

    #pragma unroll
    for (int r = 0; r < RR; ++r) {
        unsigned short* C = C_base + (size_t)r * NN * CN;
        #pragma unroll
        for (int mi = 0; mi < MF; ++mi) {
            int lrow = wr * 32 + mi * 16 + lq * 4;
            #pragma unroll
            for (int ni = 0; ni < NF; ++ni) {
                int cc = bh * 64 + wc * 32 + ni * 16 + l15;
                #pragma unroll
                for (int q = 0; q < 4; ++q) {
                    int rr = row0 + lrow + q;
                    if (rr < N)
                        C[(size_t)rr * CN + cc] =
                            (unsigned short)bf16round(acc[r][mi][ni][q] * sLds[r * BM + lrow + q]);
                }
            }
        }
    }
}

// ---------------- GEMM v6 (standalone, layer 2) ----------------
template<int K, int CN, bool A_F32>
__global__ __launch_bounds__(256) void gemm_v6_kernel(
    const void* __restrict__ Av, const unsigned short* __restrict__ Wt_base,
    const float* __restrict__ srow_base, unsigned short* __restrict__ C_base, int N)
{
    constexpr int BM  = 64;
    constexpr int BK  = 64;
    constexpr int MF  = 2;
    constexpr int NF  = 2;
    constexpr int LDA = A_F32 ? (BK + 8) : BK;

    __shared__ unsigned short As[BM * LDA];
    __shared__ unsigned short Bs[RR][64 * BK];
    __shared__ float sLds[RR][BM];

    const int tid  = threadIdx.x;
    const int wave = tid >> 6;
    const int lane = tid & 63;
    const int wr   = wave >> 1;
    const int wc   = wave & 1;
    const int row0 = blockIdx.x * BM;
    const int bh   = blockIdx.y;
    const int l15  = lane & 15;
    const int lq   = lane >> 4;

    for (int i = tid; i < RR * BM; i += 256) {
        int r  = i / BM;
        int rr = row0 + (i % BM);
        sLds[r][i % BM] = (rr < N) ? srow_base[(size_t)r * NN + rr] : 0.f;
    }

    f32x4 acc[RR][MF][NF];
    #pragma unroll
    for (int r = 0; r < RR; ++r)
        #pragma unroll
        for (int mi = 0; mi < MF; ++mi)
            #pragma unroll
            for (int ni = 0; ni < NF; ++ni)
                #pragma unroll
                for (int q = 0; q < 4; ++q) acc[r][mi][ni][q] = 0.0f;

    for (int k0 = 0; k0 < K; k0 += BK) {
        __syncthreads();
        if constexpr (A_F32) {
            const float* A = (const float*)Av;
            #pragma unroll
            for (int i = 0; i < 2; ++i) {
                int c2  = i * 256 + tid;
                int row = c2 >> 3;
                int fc  = (c2 & 7) * 2;
                float4 v0 = make_float4(0.f, 0.f, 0.f, 0.f);
                float4 v1 = make_float4(0.f, 0.f, 0.f, 0.f);
                if (row0 + row < N) {
                    const float* Ar = A + (size_t)(row0 + row) * K + k0 + fc * 4;
                    v0 = *reinterpret_cast<const float4*>(Ar);
                    v1 = *reinterpret_cast<const float4*>(Ar + 4);
                }
                uint4 o;
                o.x = pack2_bf16(v0.x, v0.y);
                o.y = pack2_bf16(v0.z, v0.w);
                o.z = pack2_bf16(v1.x, v1.y);
                o.w = pack2_bf16(v1.z, v1.w);
                *reinterpret_cast<uint4*>(&As[row * LDA + fc * 4]) = o;
            }
        } else {
            const unsigned short* A = (const unsigned short*)Av;
            #pragma unroll
            for (int i = 0; i < 2; ++i) {
                int c   = i * 256 + tid;
                int row = c >> 3;
                int kc  = c & 7;
                int kcs = kc ^ (row & 7);
                if (row0 + row < N)
                    gload_lds16(A + (size_t)(row0 + row) * K + k0 + kcs * 8, &As[c * 8]);
            }
        }
        #pragma unroll
        for (int i = 0; i < 6; ++i) {
            int c  = i * 256 + tid;
            int r  = c >> 9;
            int cc = c & 511;
            int n  = cc >> 3;
            int kc = cc & 7;
            int kcs = kc ^ (n & 7);
            gload_lds16(Wt_base + ((size_t)r * CN + bh * 64 + n) * K + k0 + kcs * 8,
                        &Bs[r][cc * 8]);
        }
        __syncthreads();

        #pragma unroll
        for (int kk = 0; kk < BK; kk += 32) {
            const int j = kk / 8 + lq;
            bf16x8 af[MF];
            #pragma unroll
            for (int mi = 0; mi < MF; ++mi) {
                int row = wr * 32 + mi * 16 + l15;
                if constexpr (A_F32)
                    af[mi] = *reinterpret_cast<const bf16x8*>(&As[row * LDA + kk + lq * 8]);
                else
                    af[mi] = *reinterpret_cast<const bf16x8*>(&As[row * BK + (j ^ (row & 7)) * 8]);
            }
            #pragma unroll
            for (int r = 0; r < RR; ++r) {
                bf16x8 bfg[NF];
                #pragma unroll
                for (int ni = 0; ni < NF; ++ni) {
                    int n = wc * 32 + ni * 16 + l15;
                    bfg[ni] = *reinterpret_cast<const bf16x8*>(&Bs[r][n * BK + (j ^ (n & 7)) * 8]);
                }
                #pragma unroll
                for (int mi = 0; mi < MF; ++mi)
                    #pragma unroll
                    for (int ni = 0; ni < NF; ++ni)
                        acc[r][mi][ni] = __builtin_amdgcn_mfma_f32_16x16x32_bf16(
                            af[mi], bfg[ni], acc[r][mi][ni], 0, 0, 0);
            }
        }
    }

    #pragma unroll
    for (int r = 0; r < RR; ++r) {
        unsigned short* C = C_base + (size_t)r * NN * CN;
        #pragma unroll
        for (int mi = 0; mi < MF; ++mi) {
            int lrow = wr * 32 + mi * 16 + lq * 4;
            #pragma unroll
            for (int ni = 0; ni < NF; ++ni) {
                int cc = bh * 64 + wc * 32 + ni * 16 + l15;
                #pragma unroll
                for (int q = 0; q < 4; ++q) {
                    int rr = row0 + lrow + q;
                    if (rr < N)
                        C[(size_t)rr * CN + cc] =
                            (unsigned short)bf16round(acc[r][mi][ni][q] * sLds[r][lrow + q]);
                }
            }
        }
    }
}

// ---------------- gather layer 1 (flat CSR, 8/4/1 ILP): h1(bf16) ----------------
__global__ __launch_bounds__(256) void gather1_kernel(
    const unsigned* __restrict__ Y, const uint2* __restrict__ col2,
    const int* __restrict__ rp_c, const float* __restrict__ b1,
    unsigned* __restrict__ h1)
{
    const int wid  = threadIdx.x >> 6;
    const int lane = threadIdx.x & 63;
    const int n    = blockIdx.x * 4 + wid;
    if (n >= NN) return;
    const int beg = rp_c[n], end = rp_c[n + 1];

    float ax[8], ay[8];
    #pragma unroll
    for (int j = 0; j < 8; ++j) { ax[j] = 0.f; ay[j] = 0.f; }

    int e = beg;
    for (; e + 7 < end; e += 8) {
        uint2 cc[8]; unsigned uu[8];
        #pragma unroll
        for (int j = 0; j < 8; ++j) cc[j] = col2[e + j];
        #pragma unroll
        for (int j = 0; j < 8; ++j) uu[j] = Y[(size_t)cc[j].x * 64 + lane];
        #pragma unroll
        for (int j = 0; j < 8; ++j) {
            float s = __uint_as_float(cc[j].y);
            ax[j] = fmaf(s, bflo(uu[j]), ax[j]);
            ay[j] = fmaf(s, bfhi(uu[j]), ay[j]);
        }
    }
    for (; e + 3 < end; e += 4) {
        uint2 cc[4]; unsigned uu[4];
        #pragma unroll
        for (int j = 0; j < 4; ++j) cc[j] = col2[e + j];
        #pragma unroll
        for (int j = 0; j < 4; ++j) uu[j] = Y[(size_t)cc[j].x * 64 + lane];
        #pragma unroll
        for (int j = 0; j < 4; ++j) {
            float s = __uint_as_float(cc[j].y);
            ax[j] = fmaf(s, bflo(uu[j]), ax[j]);
            ay[j] = fmaf(s, bfhi(uu[j]), ay[j]);
        }
    }
    for (; e < end; ++e) {
        uint2 c0 = col2[e];
        unsigned u0 = Y[(size_t)c0.x * 64 + lane];
        float s = __uint_as_float(c0.y);
        ax[0] = fmaf(s, bflo(u0), ax[0]);
        ay[0] = fmaf(s, bfhi(u0), ay[0]);
    }
    float sx = ((ax[0] + ax[1]) + (ax[2] + ax[3])) + ((ax[4] + ax[5]) + (ax[6] + ax[7]));
    float sy = ((ay[0] + ay[1]) + (ay[2] + ay[3])) + ((ay[4] + ay[5]) + (ay[6] + ay[7]));
    float bx = b1[lane * 2]     + b1[FHID + lane * 2]     + b1[2 * FHID + lane * 2];
    float by = b1[lane * 2 + 1] + b1[FHID + lane * 2 + 1] + b1[2 * FHID + lane * 2 + 1];
    const float inv = 1.0f / (float)RR;
    float ox = fmaxf((sx + bx) * inv, 0.f);
    float oy = fmaxf((sy + by) * inv, 0.f);
    h1[(size_t)n * 64 + lane] = pack2_bf16(ox, oy);
}

// ---------------- gather layer 2 (flat CSR, 8/4/1 ILP): h2(bf16) ----------------
__global__ __launch_bounds__(256) void gather2_kernel(
    const unsigned short* __restrict__ Y, const uint2* __restrict__ col2,
    const int* __restrict__ rp_c, const float* __restrict__ b2,
    unsigned short* __restrict__ h2)
{
    const int wid  = threadIdx.x >> 6;
    const int lane = threadIdx.x & 63;
    const int n    = blockIdx.x * 4 + wid;
    if (n >= NN) return;
    const int beg = rp_c[n], end = rp_c[n + 1];

    float a[8];
    #pragma unroll
    for (int j = 0; j < 8; ++j) a[j] = 0.f;

    int e = beg;
    for (; e + 7 < end; e += 8) {
        uint2 cc[8]; unsigned short uu[8];
        #pragma unroll
        for (int j = 0; j < 8; ++j) cc[j] = col2[e + j];
        #pragma unroll
        for (int j = 0; j < 8; ++j) uu[j] = Y[(size_t)cc[j].x * 64 + lane];
        #pragma unroll
        for (int j = 0; j < 8; ++j)
            a[j] = fmaf(__uint_as_float(cc[j].y),
                        __uint_as_float((unsigned)uu[j] << 16), a[j]);
    }
    for (; e + 3 < end; e += 4) {
        uint2 cc[4]; unsigned short uu[4];
        #pragma unroll
        for (int j = 0; j < 4; ++j) cc[j] = col2[e + j];
        #pragma unroll
        for (int j = 0; j < 4; ++j) uu[j] = Y[(size_t)cc[j].x * 64 + lane];
        #pragma unroll
        for (int j = 0; j < 4; ++j)
            a[j] = fmaf(__uint_as_float(cc[j].y),
                        __uint_as_float((unsigned)uu[j] << 16), a[j]);
    }
    for (; e < end; ++e) {
        uint2 c0 = col2[e];
        a[0] = fmaf(__uint_as_float(c0.y),
                    __uint_as_float((unsigned)Y[(size_t)c0.x * 64 + lane] << 16), a[0]);
    }
    float s = ((a[0] + a[1]) + (a[2] + a[3])) + ((a[4] + a[5]) + (a[6] + a[7]));
    float bs = b2[lane] + b2[FOUT + lane] + b2[2 * FOUT + lane];
    float o = (s + bs) * (1.0f / (float)RR);
    h2[(size_t)n * 64 + lane] = (unsigned short)bf16round(o);
}

// ---------------- edge dot-product scores (bf16 h2, 8 lanes/edge, uint4) ----------
__global__ __launch_bounds__(256) void score_kernel(
    const unsigned short* __restrict__ h, const int* __restrict__ src0,
    const int* __restrict__ dst0, const int* __restrict__ nsrc,
    const int* __restrict__ ndst, float* __restrict__ out)
{
    int idx = blockIdx.x * 256 + threadIdx.x;  // grid exact: 2*E*8
    int e = idx >> 3;
    int l = idx & 7;
    int u, v;
    if (e < EE) { u = src0[e]; v = dst0[e]; }
    else        { u = nsrc[e - EE]; v = ndst[e - EE]; }
    uint4 a = *reinterpret_cast<const uint4*>(&h[(size_t)u * FOUT + l * 8]);
    uint4 b = *reinterpret_cast<const uint4*>(&h[(size_t)v * FOUT + l * 8]);
    float p = bflo(a.x) * bflo(b.x) + bfhi(a.x) * bfhi(b.x)
            + bflo(a.y) * bflo(b.y) + bfhi(a.y) * bfhi(b.y)
            + bflo(a.z) * bflo(b.z) + bfhi(a.z) * bfhi(b.z)
            + bflo(a.w) * bflo(b.w) + bfhi(a.w) * bfhi(b.w);
    p += __shfl_xor(p, 4, 8);
    p += __shfl_xor(p, 2, 8);
    p += __shfl_xor(p, 1, 8);
    if (l == 0) out[e] = p;
}

// ---------------- launch ----------------
extern "C" void kernel_launch(void* const* d_in, const int* in_sizes, int n_in,
                              void* d_out, int out_size, void* d_ws, size_t ws_size,
                              hipStream_t stream)
{
    const float* feature = (const float*)d_in[0];
    const float* W1      = (const float*)d_in[1];
    const float* b1      = (const float*)d_in[2];
    const float* W2      = (const float*)d_in[3];
    const float* b2      = (const float*)d_in[4];
    const int*   src     = (const int*)d_in[5];
    const int*   dst     = (const int*)d_in[6];
    const int*   nsrc    = (const int*)d_in[7];
    const int*   ndst    = (const int*)d_in[8];
    float* out = (float*)d_out;

    // workspace (~132 MB); Yu union: ushort partials (30+30 MB) + base_c -> Y1/Y2
    char* p = (char*)d_ws;
    float* s_out   = (float*)p; p += sizeof(float) * RR * NN;
    float* s_in    = (float*)p; p += sizeof(float) * RR * NN;
    unsigned* h1   = (unsigned*)p; p += sizeof(unsigned) * (size_t)NN * 64;   // bf16x2
    unsigned short* h2 = (unsigned short*)p; p += sizeof(unsigned short) * (size_t)NN * FOUT;
    char*  Yu      = p;         p += (size_t)RR * NN * FHID * 2;              // 76.8 MB union
    int*   deg_in  = (int*)p;   p += sizeof(int) * RR * NN;
    int*   rp_c    = (int*)p;   p += sizeof(int) * (NN + 1);
    uint2* col2    = (uint2*)p; p += sizeof(uint2) * (size_t)EEC;             // 12 MB
    int*   bsum    = (int*)p;   p += sizeof(int) * NB;
    unsigned short* Wt1 = (unsigned short*)p; p += sizeof(unsigned short) * RR * FIN * FHID;
    unsigned short* Wt2 = (unsigned short*)p; p += sizeof(unsigned short) * RR * FHID * FOUT;

    unsigned short* Y1 = (unsigned short*)Yu;                      // R x N x 128 bf16
    unsigned short* Y2 = (unsigned short*)Yu;                      // R x N x 64 bf16
    unsigned short* partial_in  = (unsigned short*)Yu;             // GH x R x N u16 (30 MB)
    unsigned short* partial_out = partial_in + (size_t)GH * RR * NN; // 30 MB
    int* base_c = (int*)partial_out;                               // GH x N int (20 MB, after reduce)

    // ---- prep + CSR build (no global atomics) ----
    convw_kernel<<<(RR * FIN * FHID + RR * FHID * FOUT + 255) / 256, 256, 0, stream>>>(
        W1, Wt1, W2, Wt2);
    hist_deg_kernel<<<2 * RR * NCHUNK * GH, 512, 0, stream>>>(
        src, dst, partial_in, partial_out);
    reduce_deg_kernel<<<(2 * RR * NN + 255) / 256, 256, 0, stream>>>(
        partial_in, partial_out, deg_in, s_in, s_out);
    scan_reduce_kernel<<<NB, 1024, 0, stream>>>(deg_in, bsum);
    scan_spine_kernel<<<1, 64, 0, stream>>>(bsum);
    scan_final_kernel<<<NB, 1024, 0, stream>>>(deg_in, bsum, rp_c);
    slice_off_kernel<<<(NN + 255) / 256, 256, 0, stream>>>(rp_c, partial_in, base_c);

    const int node_grid = (NN + 3) / 4;
    const int gemm_gx = (NN + 63) / 64;    // 1563

    // ---- MEGA: fill3 (800 blocks) + layer-1 GEMM (1563*2 blocks) in one dispatch ----
    mega_fill_gemm_kernel<FIN, FHID, true><<<FILL_BLOCKS + gemm_gx * 2, 256, 0, stream>>>(
        src, dst, base_c, s_in, col2,
        feature, Wt1, s_out, Y1, NN, gemm_gx);

    gather1_kernel<<<node_grid, 256, 0, stream>>>(
        (const unsigned*)Y1, col2, rp_c, b1, h1);

    // ---- layer 2: Y2_r = bf16(diag(s_out_r)*h1 @ W2_r); h2 = mean ----
    gemm_v6_kernel<FHID, FOUT, false><<<dim3(gemm_gx, 1), 256, 0, stream>>>(
        h1, Wt2, s_out, Y2, NN);
    gather2_kernel<<<node_grid, 256, 0, stream>>>(
        Y2, col2, rp_c, b2, h2);

    // ---- scores ----
    score_kernel<<<(2 * EE * 8) / 256, 256, 0, stream>>>(h2, src, dst, nsrc, ndst, out);
}

// Round 23
// 331.813 us; speedup vs baseline: 1.0352x; 1.0352x over previous
//
#include <hip/hip_runtime.h>

// ---- problem constants (match reference) ----
namespace {
constexpr int NN   = 100000;  // nodes
constexpr int RR   = 3;       // relations
constexpr int EE   = 500000;  // edges per relation
constexpr int FIN  = 256;
constexpr int FHID = 128;
constexpr int FOUT = 64;
constexpr int EEC  = RR * EE;                         // combined edges
constexpr int SCAN_TILE = 4096;                       // elems per scan block
constexpr int NB = (NN + SCAN_TILE - 1) / SCAN_TILE;  // 25 blocks (combined scan)
// histogram geometry (counts fit ushort: per-slice per-node deg <= SLICE < 65536)
constexpr int NCHUNK  = 8;                 // hist chunks (12500 nodes, 50 KB LDS)
constexpr int CH      = NN / NCHUNK;
constexpr int GH      = 50;                // edge slices; SLICE*4B is 16B-aligned
constexpr int SLICE   = EE / GH;           // 10000
// fill geometry (12500-node chunks, 50 KB LDS, 1024 thr, grid 400; 8 passes not 16)
constexpr int NCHUNK_F = 8;
constexpr int CH_F     = NN / NCHUNK_F;    // 12500
}

typedef float f32x4  __attribute__((ext_vector_type(4)));
typedef short bf16x8 __attribute__((ext_vector_type(8)));

__device__ inline unsigned bf16round(float a) {
    unsigned u = __float_as_uint(a);
    return (u + 0x7FFFu + ((u >> 16) & 1u)) >> 16;   // RNE
}
__device__ inline unsigned pack2_bf16(float a, float b) {
    return bf16round(a) | (bf16round(b) << 16);
}
__device__ inline float bflo(unsigned u) { return __uint_as_float(u << 16); }
__device__ inline float bfhi(unsigned u) { return __uint_as_float(u & 0xFFFF0000u); }

// async global->LDS 16B copy (linear dest: wave base + lane*16)
__device__ inline void gload_lds16(const unsigned short* g, unsigned short* l) {
    __builtin_amdgcn_global_load_lds(
        (const __attribute__((address_space(1))) void*)g,
        (__attribute__((address_space(3))) void*)l, 16, 0, 0);
}

// ---------------- fused weight transpose+convert: Wt[r][m][k] = bf16(W[r][k][m]) ----
__global__ __launch_bounds__(256) void convw_kernel(
    const float* __restrict__ W1, unsigned short* __restrict__ Wt1,
    const float* __restrict__ W2, unsigned short* __restrict__ Wt2)
{
    int idx = blockIdx.x * 256 + threadIdx.x;
    const int n1 = RR * FIN * FHID;
    const int n2 = RR * FHID * FOUT;
    if (idx < n1) {
        int r = idx / (FIN * FHID);
        int rem = idx - r * FIN * FHID;
        int k = rem / FHID, m = rem - k * FHID;
        Wt1[((size_t)r * FHID + m) * FIN + k] = (unsigned short)bf16round(W1[idx]);
    } else if (idx - n1 < n2) {
        int j = idx - n1;
        int r = j / (FHID * FOUT);
        int rem = j - r * FHID * FOUT;
        int k = rem / FOUT, m = rem - k * FOUT;
        Wt2[((size_t)r * FOUT + m) * FHID + k] = (unsigned short)bf16round(W2[j]);
    }
}

// ---------------- LDS-histogram degree count (int4 edges, ushort partials) ----
// grid: 2(dir) x RR x NCHUNK x GH = 2400 blocks, 512 threads
__global__ __launch_bounds__(512) void hist_deg_kernel(
    const int* __restrict__ src, const int* __restrict__ dst,
    unsigned short* __restrict__ partial_in, unsigned short* __restrict__ partial_out)
{
    __shared__ int cnt[CH];   // 50 KB
    const int b   = blockIdx.x;
    const int dir = b / (RR * NCHUNK * GH);
    const int rem = b % (RR * NCHUNK * GH);
    const int r   = rem / (NCHUNK * GH);
    const int c   = (rem / GH) % NCHUNK;
    const int g   = rem % GH;
    const int tid = threadIdx.x;

    for (int i = tid; i < CH; i += 512) cnt[i] = 0;
    __syncthreads();

    const int* ids = (dir ? src : dst) + (size_t)r * EE + (size_t)g * SLICE;
    const int base = c * CH;
    for (int i4 = tid; i4 < SLICE / 4; i4 += 512) {
        int4 q = reinterpret_cast<const int4*>(ids)[i4];
        int d;
        d = q.x - base; if ((unsigned)d < (unsigned)CH) atomicAdd(&cnt[d], 1);
        d = q.y - base; if ((unsigned)d < (unsigned)CH) atomicAdd(&cnt[d], 1);
        d = q.z - base; if ((unsigned)d < (unsigned)CH) atomicAdd(&cnt[d], 1);
        d = q.w - base; if ((unsigned)d < (unsigned)CH) atomicAdd(&cnt[d], 1);
    }
    __syncthreads();

    unsigned short* part = (dir ? partial_out : partial_in)
                           + (size_t)g * RR * NN + (size_t)r * NN + base;
    for (int i = tid; i < CH; i += 512) part[i] = (unsigned short)cnt[i];
}

// reduce partials -> deg_in + s_in (dir 0) / s_out (dir 1)
__global__ __launch_bounds__(256) void reduce_deg_kernel(
    const unsigned short* __restrict__ partial_in,
    const unsigned short* __restrict__ partial_out,
    int* __restrict__ deg_in, float* __restrict__ s_in, float* __restrict__ s_out)
{
    int idx = blockIdx.x * 256 + threadIdx.x;
    if (idx >= 2 * RR * NN) return;
    int dir = idx / (RR * NN);
    int j   = idx % (RR * NN);
    const unsigned short* part = dir ? partial_out : partial_in;
    int s = 0;
    #pragma unroll
    for (int g = 0; g < GH; ++g) s += part[(size_t)g * RR * NN + j];
    float v = rsqrtf((float)max(s, 1));
    if (dir == 0) { deg_in[j] = s; s_in[j] = v; }
    else          { s_out[j] = v; }
}

// ---------------- scan over COMBINED degrees -> rp_c ----------------
__global__ __launch_bounds__(1024) void scan_reduce_kernel(
    const int* __restrict__ deg_in, int* __restrict__ bsum)
{
    const int b = blockIdx.x;
    const int t = threadIdx.x;
    int n0 = b * SCAN_TILE + t * 4;
    int s = 0;
    if (n0 + 3 < NN) {
        int4 a = *reinterpret_cast<const int4*>(&deg_in[n0]);
        int4 bq = *reinterpret_cast<const int4*>(&deg_in[NN + n0]);
        int4 cq = *reinterpret_cast<const int4*>(&deg_in[2 * NN + n0]);
        s = a.x + a.y + a.z + a.w + bq.x + bq.y + bq.z + bq.w + cq.x + cq.y + cq.z + cq.w;
    } else {
        for (int i = 0; i < 4; ++i)
            if (n0 + i < NN)
                s += deg_in[n0 + i] + deg_in[NN + n0 + i] + deg_in[2 * NN + n0 + i];
    }
    __shared__ int sh[1024];
    sh[t] = s;
    __syncthreads();
    for (int off = 512; off > 0; off >>= 1) {
        if (t < off) sh[t] += sh[t + off];
        __syncthreads();
    }
    if (t == 0) bsum[b] = sh[0];
}

__global__ void scan_spine_kernel(int* __restrict__ bsum)
{
    if (threadIdx.x != 0 || blockIdx.x != 0) return;
    int run = 0;
    for (int i = 0; i < NB; ++i) {
        int v = bsum[i];
        bsum[i] = run;
        run += v;
    }
}

__global__ __launch_bounds__(1024) void scan_final_kernel(
    const int* __restrict__ deg_in, const int* __restrict__ bsum,
    int* __restrict__ rp_c)
{
    const int b = blockIdx.x;
    const int t = threadIdx.x;
    int n0 = b * SCAN_TILE + t * 4;
    int v[4] = {0, 0, 0, 0};
    for (int i = 0; i < 4; ++i)
        if (n0 + i < NN)
            v[i] = deg_in[n0 + i] + deg_in[NN + n0 + i] + deg_in[2 * NN + n0 + i];
    int s = v[0] + v[1] + v[2] + v[3];
    __shared__ int sh[1024];
    sh[t] = s;
    __syncthreads();
    for (int off = 1; off < 1024; off <<= 1) {
        int x = (t >= off) ? sh[t - off] : 0;
        __syncthreads();
        if (t >= off) sh[t] += x;
        __syncthreads();
    }
    int off = bsum[b] + sh[t] - s;
    for (int i = 0; i < 4; ++i) {
        if (n0 + i < NN) { rp_c[n0 + i] = off; off += v[i]; }
    }
    if (b == NB - 1 && t == 0) rp_c[NN] = EEC;
}

// ---------------- combined slice bases: base_c[g][n] ----------------
__global__ __launch_bounds__(256) void slice_off_kernel(
    const int* __restrict__ rp_c, const unsigned short* __restrict__ partial_in,
    int* __restrict__ base_c)
{
    int n = blockIdx.x * 256 + threadIdx.x;
    if (n >= NN) return;
    int base = rp_c[n];
    #pragma unroll
    for (int g = 0; g < GH; ++g) {
        base_c[(size_t)g * NN + n] = base;
        const unsigned short* p = partial_in + (size_t)g * RR * NN + n;
        base += (int)p[0] + (int)p[NN] + (int)p[2 * NN];
    }
}

// ---------------- combined atomic-free CSR fill (1024 thr, int4 edges) ----------
// NCHUNK_F=8 (12500-node chunks, 50 KB LDS): 8 edge passes instead of 16 ->
// 192 MB read traffic instead of 384 MB. grid 8x50 = 400 blocks.
__global__ __launch_bounds__(1024) void fill3_kernel(
    const int* __restrict__ src, const int* __restrict__ dst,
    const int* __restrict__ base_c, const float* __restrict__ s_in,
    uint2* __restrict__ col2)
{
    __shared__ int cur[CH_F];   // 50 KB
    const int b   = blockIdx.x;
    const int c   = b / GH;
    const int g   = b % GH;
    const int tid = threadIdx.x;
    const int base = c * CH_F;

    const int* so = base_c + (size_t)g * NN + base;
    for (int i = tid; i < CH_F; i += 1024) cur[i] = so[i];
    __syncthreads();

    for (int r = 0; r < RR; ++r) {
        const int* ds = dst + (size_t)r * EE + (size_t)g * SLICE;
        const int* ss = src + (size_t)r * EE + (size_t)g * SLICE;
        const float* si = s_in + (size_t)r * NN;
        const unsigned rbase = (unsigned)(r * NN);
        for (int i4 = tid; i4 < SLICE / 4; i4 += 1024) {
            int4 d4 = reinterpret_cast<const int4*>(ds)[i4];
            int4 s4 = reinterpret_cast<const int4*>(ss)[i4];
            int dl;
            dl = d4.x - base;
            if ((unsigned)dl < (unsigned)CH_F) {
                int pos = atomicAdd(&cur[dl], 1);
                col2[pos] = make_uint2(rbase + (unsigned)s4.x, __float_as_uint(si[d4.x]));
            }
            dl = d4.y - base;
            if ((unsigned)dl < (unsigned)CH_F) {
                int pos = atomicAdd(&cur[dl], 1);
                col2[pos] = make_uint2(rbase + (unsigned)s4.y, __float_as_uint(si[d4.y]));
            }
            dl = d4.z - base;
            if ((unsigned)dl < (unsigned)CH_F) {
                int pos = atomicAdd(&cur[dl], 1);
                col2[pos] = make_uint2(rbase + (unsigned)s4.z, __float_as_uint(si[d4.z]));
            }
            dl = d4.w - base;
            if ((unsigned)dl < (unsigned)CH_F) {
                int pos = atomicAdd(&cur[dl], 1);
                col2[pos] = make_uint2(rbase + (unsigned)s4.w, __float_as_uint(si[d4.w]));
            }
        }
    }
}

// ---------------- GEMM v6: BM=64, BN=64, BK=64, 2x2 waves ----------------
template<int K, int CN, bool A_F32>
__global__ __launch_bounds__(256) void gemm_v6_kernel(
    const void* __restrict__ Av, const unsigned short* __restrict__ Wt_base,
    const float* __restrict__ srow_base, unsigned short* __restrict__ C_base, int N)
{
    constexpr int BM  = 64;
    constexpr int BK  = 64;
    constexpr int MF  = 2;
    constexpr int NF  = 2;
    constexpr int LDA = A_F32 ? (BK + 8) : BK;

    __shared__ unsigned short As[BM * LDA];      // 9.2 / 8 KB
    __shared__ unsigned short Bs[RR][64 * BK];   // 24.5 KB
    __shared__ float sLds[RR][BM];               // 768 B

    const int tid  = threadIdx.x;
    const int wave = tid >> 6;
    const int lane = tid & 63;
    const int wr   = wave >> 1;
    const int wc   = wave & 1;
    const int row0 = blockIdx.x * BM;
    const int bh   = blockIdx.y;                 // 64-col half
    const int l15  = lane & 15;
    const int lq   = lane >> 4;

    for (int i = tid; i < RR * BM; i += 256) {
        int r  = i / BM;
        int rr = row0 + (i % BM);
        sLds[r][i % BM] = (rr < N) ? srow_base[(size_t)r * NN + rr] : 0.f;
    }

    f32x4 acc[RR][MF][NF];
    #pragma unroll
    for (int r = 0; r < RR; ++r)
        #pragma unroll
        for (int mi = 0; mi < MF; ++mi)
            #pragma unroll
            for (int ni = 0; ni < NF; ++ni)
                #pragma unroll
                for (int q = 0; q < 4; ++q) acc[r][mi][ni][q] = 0.0f;

    for (int k0 = 0; k0 < K; k0 += BK) {
        __syncthreads();
        // ---- stage A tile (64 rows x 64 k) ----
        if constexpr (A_F32) {
            const float* A = (const float*)Av;
            #pragma unroll
            for (int i = 0; i < 2; ++i) {
                int c2  = i * 256 + tid;       // 0..511
                int row = c2 >> 3;
                int fc  = (c2 & 7) * 2;
                float4 v0 = make_float4(0.f, 0.f, 0.f, 0.f);
                float4 v1 = make_float4(0.f, 0.f, 0.f, 0.f);
                if (row0 + row < N) {
                    const float* Ar = A + (size_t)(row0 + row) * K + k0 + fc * 4;
                    v0 = *reinterpret_cast<const float4*>(Ar);
                    v1 = *reinterpret_cast<const float4*>(Ar + 4);
                }
                uint4 o;
                o.x = pack2_bf16(v0.x, v0.y);
                o.y = pack2_bf16(v0.z, v0.w);
                o.z = pack2_bf16(v1.x, v1.y);
                o.w = pack2_bf16(v1.z, v1.w);
                *reinterpret_cast<uint4*>(&As[row * LDA + fc * 4]) = o;
            }
        } else {
            const unsigned short* A = (const unsigned short*)Av;
            #pragma unroll
            for (int i = 0; i < 2; ++i) {
                int c   = i * 256 + tid;       // 0..511
                int row = c >> 3;
                int kc  = c & 7;
                int kcs = kc ^ (row & 7);
                if (row0 + row < N)
                    gload_lds16(A + (size_t)(row0 + row) * K + k0 + kcs * 8, &As[c * 8]);
            }
        }
        // ---- stage B tiles (3 relations x 64 n x 64 k) ----
        #pragma unroll
        for (int i = 0; i < 6; ++i) {
            int c  = i * 256 + tid;        // 0..1535
            int r  = c >> 9;
            int cc = c & 511;
            int n  = cc >> 3;
            int kc = cc & 7;
            int kcs = kc ^ (n & 7);
            gload_lds16(Wt_base + ((size_t)r * CN + bh * 64 + n) * K + k0 + kcs * 8,
                        &Bs[r][cc * 8]);
        }
        __syncthreads();

        #pragma unroll
        for (int kk = 0; kk < BK; kk += 32) {
            const int j = kk / 8 + lq;
            bf16x8 af[MF];
            #pragma unroll
            for (int mi = 0; mi < MF; ++mi) {
                int row = wr * 32 + mi * 16 + l15;
                if constexpr (A_F32)
                    af[mi] = *reinterpret_cast<const bf16x8*>(&As[row * LDA + kk + lq * 8]);
                else
                    af[mi] = *reinterpret_cast<const bf16x8*>(&As[row * BK + (j ^ (row & 7)) * 8]);
            }
            #pragma unroll
            for (int r = 0; r < RR; ++r) {
                bf16x8 bfg[NF];
                #pragma unroll
                for (int ni = 0; ni < NF; ++ni) {
                    int n = wc * 32 + ni * 16 + l15;
                    bfg[ni] = *reinterpret_cast<const bf16x8*>(&Bs[r][n * BK + (j ^ (n & 7)) * 8]);
                }
                #pragma unroll
                for (int mi = 0; mi < MF; ++mi)
                    #pragma unroll
                    for (int ni = 0; ni < NF; ++ni)
                        acc[r][mi][ni] = __builtin_amdgcn_mfma_f32_16x16x32_bf16(
                            af[mi], bfg[ni], acc[r][mi][ni], 0, 0, 0);
            }
        }
    }

    // ---- epilogue: scale rows by s_out_r, write C (bf16) ----
    #pragma unroll
    for (int r = 0; r < RR; ++r) {
        unsigned short* C = C_base + (size_t)r * NN * CN;
        #pragma unroll
        for (int mi = 0; mi < MF; ++mi) {
            int lrow = wr * 32 + mi * 16 + lq * 4;
            #pragma unroll
            for (int ni = 0; ni < NF; ++ni) {
                int cc = bh * 64 + wc * 32 + ni * 16 + l15;
                #pragma unroll
                for (int q = 0; q < 4; ++q) {
                    int rr = row0 + lrow + q;
                    if (rr < N)
                        C[(size_t)rr * CN + cc] =
                            (unsigned short)bf16round(acc[r][mi][ni][q] * sLds[r][lrow + q]);
                }
            }
        }
    }
}

// ---------------- gather layer 1 (flat CSR, 8/4/1 ILP): h1(bf16) ----------------
__global__ __launch_bounds__(256) void gather1_kernel(
    const unsigned* __restrict__ Y, const uint2* __restrict__ col2,
    const int* __restrict__ rp_c, const float* __restrict__ b1,
    unsigned* __restrict__ h1)
{
    const int wid  = threadIdx.x >> 6;
    const int lane = threadIdx.x & 63;
    const int n    = blockIdx.x * 4 + wid;
    if (n >= NN) return;
    const int beg = rp_c[n], end = rp_c[n + 1];

    float ax[8], ay[8];
    #pragma unroll
    for (int j = 0; j < 8; ++j) { ax[j] = 0.f; ay[j] = 0.f; }

    int e = beg;
    for (; e + 7 < end; e += 8) {
        uint2 cc[8]; unsigned uu[8];
        #pragma unroll
        for (int j = 0; j < 8; ++j) cc[j] = col2[e + j];
        #pragma unroll
        for (int j = 0; j < 8; ++j) uu[j] = Y[(size_t)cc[j].x * 64 + lane];
        #pragma unroll
        for (int j = 0; j < 8; ++j) {
            float s = __uint_as_float(cc[j].y);
            ax[j] = fmaf(s, bflo(uu[j]), ax[j]);
            ay[j] = fmaf(s, bfhi(uu[j]), ay[j]);
        }
    }
    for (; e + 3 < end; e += 4) {
        uint2 cc[4]; unsigned uu[4];
        #pragma unroll
        for (int j = 0; j < 4; ++j) cc[j] = col2[e + j];
        #pragma unroll
        for (int j = 0; j < 4; ++j) uu[j] = Y[(size_t)cc[j].x * 64 + lane];
        #pragma unroll
        for (int j = 0; j < 4; ++j) {
            float s = __uint_as_float(cc[j].y);
            ax[j] = fmaf(s, bflo(uu[j]), ax[j]);
            ay[j] = fmaf(s, bfhi(uu[j]), ay[j]);
        }
    }
    for (; e < end; ++e) {
        uint2 c0 = col2[e];
        unsigned u0 = Y[(size_t)c0.x * 64 + lane];
        float s = __uint_as_float(c0.y);
        ax[0] = fmaf(s, bflo(u0), ax[0]);
        ay[0] = fmaf(s, bfhi(u0), ay[0]);
    }
    float sx = ((ax[0] + ax[1]) + (ax[2] + ax[3])) + ((ax[4] + ax[5]) + (ax[6] + ax[7]));
    float sy = ((ay[0] + ay[1]) + (ay[2] + ay[3])) + ((ay[4] + ay[5]) + (ay[6] + ay[7]));
    float bx = b1[lane * 2]     + b1[FHID + lane * 2]     + b1[2 * FHID + lane * 2];
    float by = b1[lane * 2 + 1] + b1[FHID + lane * 2 + 1] + b1[2 * FHID + lane * 2 + 1];
    const float inv = 1.0f / (float)RR;
    float ox = fmaxf((sx + bx) * inv, 0.f);
    float oy = fmaxf((sy + by) * inv, 0.f);
    h1[(size_t)n * 64 + lane] = pack2_bf16(ox, oy);
}

// ---------------- gather layer 2 (flat CSR, 8/4/1 ILP): h2(bf16) ----------------
__global__ __launch_bounds__(256) void gather2_kernel(
    const unsigned short* __restrict__ Y, const uint2* __restrict__ col2,
    const int* __restrict__ rp_c, const float* __restrict__ b2,
    unsigned short* __restrict__ h2)
{
    const int wid  = threadIdx.x >> 6;
    const int lane = threadIdx.x & 63;
    const int n    = blockIdx.x * 4 + wid;
    if (n >= NN) return;
    const int beg = rp_c[n], end = rp_c[n + 1];

    float a[8];
    #pragma unroll
    for (int j = 0; j < 8; ++j) a[j] = 0.f;

    int e = beg;
    for (; e + 7 < end; e += 8) {
        uint2 cc[8]; unsigned short uu[8];
        #pragma unroll
        for (int j = 0; j < 8; ++j) cc[j] = col2[e + j];
        #pragma unroll
        for (int j = 0; j < 8; ++j) uu[j] = Y[(size_t)cc[j].x * 64 + lane];
        #pragma unroll
        for (int j = 0; j < 8; ++j)
            a[j] = fmaf(__uint_as_float(cc[j].y),
                        __uint_as_float((unsigned)uu[j] << 16), a[j]);
    }
    for (; e + 3 < end; e += 4) {
        uint2 cc[4]; unsigned short uu[4];
        #pragma unroll
        for (int j = 0; j < 4; ++j) cc[j] = col2[e + j];
        #pragma unroll
        for (int j = 0; j < 4; ++j) uu[j] = Y[(size_t)cc[j].x * 64 + lane];
        #pragma unroll
        for (int j = 0; j < 4; ++j)
            a[j] = fmaf(__uint_as_float(cc[j].y),
                        __uint_as_float((unsigned)uu[j] << 16), a[j]);
    }
    for (; e < end; ++e) {
        uint2 c0 = col2[e];
        a[0] = fmaf(__uint_as_float(c0.y),
                    __uint_as_float((unsigned)Y[(size_t)c0.x * 64 + lane] << 16), a[0]);
    }
    float s = ((a[0] + a[1]) + (a[2] + a[3])) + ((a[4] + a[5]) + (a[6] + a[7]));
    float bs = b2[lane] + b2[FOUT + lane] + b2[2 * FOUT + lane];
    float o = (s + bs) * (1.0f / (float)RR);
    h2[(size_t)n * 64 + lane] = (unsigned short)bf16round(o);
}

// ---------------- edge dot-product scores (bf16 h2, 8 lanes/edge, uint4) ----------
__global__ __launch_bounds__(256) void score_kernel(
    const unsigned short* __restrict__ h, const int* __restrict__ src0,
    const int* __restrict__ dst0, const int* __restrict__ nsrc,
    const int* __restrict__ ndst, float* __restrict__ out)
{
    int idx = blockIdx.x * 256 + threadIdx.x;  // grid exact: 2*E*8
    int e = idx >> 3;
    int l = idx & 7;
    int u, v;
    if (e < EE) { u = src0[e]; v = dst0[e]; }
    else        { u = nsrc[e - EE]; v = ndst[e - EE]; }
    uint4 a = *reinterpret_cast<const uint4*>(&h[(size_t)u * FOUT + l * 8]);
    uint4 b = *reinterpret_cast<const uint4*>(&h[(size_t)v * FOUT + l * 8]);
    float p = bflo(a.x) * bflo(b.x) + bfhi(a.x) * bfhi(b.x)
            + bflo(a.y) * bflo(b.y) + bfhi(a.y) * bfhi(b.y)
            + bflo(a.z) * bflo(b.z) + bfhi(a.z) * bfhi(b.z)
            + bflo(a.w) * bflo(b.w) + bfhi(a.w) * bfhi(b.w);
    p += __shfl_xor(p, 4, 8);
    p += __shfl_xor(p, 2, 8);
    p += __shfl_xor(p, 1, 8);
    if (l == 0) out[e] = p;
}

// ---------------- launch ----------------
extern "C" void kernel_launch(void* const* d_in, const int* in_sizes, int n_in,
                              void* d_out, int out_size, void* d_ws, size_t ws_size,
                              hipStream_t stream)
{
    const float* feature = (const float*)d_in[0];
    const float* W1      = (const float*)d_in[1];
    const float* b1      = (const float*)d_in[2];
    const float* W2      = (const float*)d_in[3];
    const float* b2      = (const float*)d_in[4];
    const int*   src     = (const int*)d_in[5];
    const int*   dst     = (const int*)d_in[6];
    const int*   nsrc    = (const int*)d_in[7];
    const int*   ndst    = (const int*)d_in[8];
    float* out = (float*)d_out;

    // workspace (~132 MB); Yu union: ushort partials (30+30 MB) + base_c -> Y1/Y2
    char* p = (char*)d_ws;
    float* s_out   = (float*)p; p += sizeof(float) * RR * NN;
    float* s_in    = (float*)p; p += sizeof(float) * RR * NN;
    unsigned* h1   = (unsigned*)p; p += sizeof(unsigned) * (size_t)NN * 64;   // bf16x2
    unsigned short* h2 = (unsigned short*)p; p += sizeof(unsigned short) * (size_t)NN * FOUT;
    char*  Yu      = p;         p += (size_t)RR * NN * FHID * 2;              // 76.8 MB union
    int*   deg_in  = (int*)p;   p += sizeof(int) * RR * NN;
    int*   rp_c    = (int*)p;   p += sizeof(int) * (NN + 1);
    uint2* col2    = (uint2*)p; p += sizeof(uint2) * (size_t)EEC;             // 12 MB
    int*   bsum    = (int*)p;   p += sizeof(int) * NB;
    unsigned short* Wt1 = (unsigned short*)p; p += sizeof(unsigned short) * RR * FIN * FHID;
    unsigned short* Wt2 = (unsigned short*)p; p += sizeof(unsigned short) * RR * FHID * FOUT;

    unsigned short* Y1 = (unsigned short*)Yu;                      // R x N x 128 bf16
    unsigned short* Y2 = (unsigned short*)Yu;                      // R x N x 64 bf16
    unsigned short* partial_in  = (unsigned short*)Yu;             // GH x R x N u16 (30 MB)
    unsigned short* partial_out = partial_in + (size_t)GH * RR * NN; // 30 MB
    int* base_c = (int*)partial_out;                               // GH x N int (20 MB, after reduce)

    // ---- prep + CSR build (no global atomics) ----
    convw_kernel<<<(RR * FIN * FHID + RR * FHID * FOUT + 255) / 256, 256, 0, stream>>>(
        W1, Wt1, W2, Wt2);
    hist_deg_kernel<<<2 * RR * NCHUNK * GH, 512, 0, stream>>>(
        src, dst, partial_in, partial_out);
    reduce_deg_kernel<<<(2 * RR * NN + 255) / 256, 256, 0, stream>>>(
        partial_in, partial_out, deg_in, s_in, s_out);
    scan_reduce_kernel<<<NB, 1024, 0, stream>>>(deg_in, bsum);
    scan_spine_kernel<<<1, 64, 0, stream>>>(bsum);
    scan_final_kernel<<<NB, 1024, 0, stream>>>(deg_in, bsum, rp_c);
    slice_off_kernel<<<(NN + 255) / 256, 256, 0, stream>>>(rp_c, partial_in, base_c);
    fill3_kernel<<<NCHUNK_F * GH, 1024, 0, stream>>>(src, dst, base_c, s_in, col2);

    const int node_grid = (NN + 3) / 4;
    const int gemm_gx = (NN + 63) / 64;

    // ---- layer 1: Y1_r = bf16(diag(s_out_r)*feature @ W1_r); h1 = relu(mean) ----
    gemm_v6_kernel<FIN, FHID, true><<<dim3(gemm_gx, 2), 256, 0, stream>>>(
        feature, Wt1, s_out, Y1, NN);
    gather1_kernel<<<node_grid, 256, 0, stream>>>(
        (const unsigned*)Y1, col2, rp_c, b1, h1);

    // ---- layer 2: Y2_r = bf16(diag(s_out_r)*h1 @ W2_r); h2 = mean ----
    gemm_v6_kernel<FHID, FOUT, false><<<dim3(gemm_gx, 1), 256, 0, stream>>>(
        h1, Wt2, s_out, Y2, NN);
    gather2_kernel<<<node_grid, 256, 0, stream>>>(
        Y2, col2, rp_c, b2, h2);

    // ---- scores ----
    score_kernel<<<(2 * EE * 8) / 256, 256, 0, stream>>>(h2, src, dst, nsrc, ndst, out);
}

// Round 24
// 329.860 us; speedup vs baseline: 1.0413x; 1.0059x over previous
//
#include <hip/hip_runtime.h>

// ---- problem constants (match reference) ----
namespace {
constexpr int NN   = 100000;  // nodes
constexpr int RR   = 3;       // relations
constexpr int EE   = 500000;  // edges per relation
constexpr int FIN  = 256;
constexpr int FHID = 128;
constexpr int FOUT = 64;
constexpr int EEC  = RR * EE;                         // combined edges
constexpr int SCAN_TILE = 4096;                       // elems per scan block
constexpr int NB = (NN + SCAN_TILE - 1) / SCAN_TILE;  // 25 blocks (combined scan)
// histogram geometry: packed u16 counters (counts <= SLICE < 65536), 25000-node
// chunks in 50 KB LDS -> only 4 edge passes (96 MB reads vs 192 MB at int cnt)
constexpr int NCHUNK_H = 4;
constexpr int CH_H     = NN / NCHUNK_H;    // 25000
constexpr int GH       = 50;               // edge slices; SLICE*4B is 16B-aligned
constexpr int SLICE    = EE / GH;          // 10000
// fill geometry (12500-node chunks, 50 KB LDS, 1024 thr, grid 400; 8 passes)
constexpr int NCHUNK_F = 8;
constexpr int CH_F     = NN / NCHUNK_F;    // 12500
}

typedef float f32x4  __attribute__((ext_vector_type(4)));
typedef short bf16x8 __attribute__((ext_vector_type(8)));

__device__ inline unsigned bf16round(float a) {
    unsigned u = __float_as_uint(a);
    return (u + 0x7FFFu + ((u >> 16) & 1u)) >> 16;   // RNE
}
__device__ inline unsigned pack2_bf16(float a, float b) {
    return bf16round(a) | (bf16round(b) << 16);
}
__device__ inline float bflo(unsigned u) { return __uint_as_float(u << 16); }
__device__ inline float bfhi(unsigned u) { return __uint_as_float(u & 0xFFFF0000u); }

// async global->LDS 16B copy (linear dest: wave base + lane*16)
__device__ inline void gload_lds16(const unsigned short* g, unsigned short* l) {
    __builtin_amdgcn_global_load_lds(
        (const __attribute__((address_space(1))) void*)g,
        (__attribute__((address_space(3))) void*)l, 16, 0, 0);
}

// ---------------- fused weight transpose+convert: Wt[r][m][k] = bf16(W[r][k][m]) ----
__global__ __launch_bounds__(256) void convw_kernel(
    const float* __restrict__ W1, unsigned short* __restrict__ Wt1,
    const float* __restrict__ W2, unsigned short* __restrict__ Wt2)
{
    int idx = blockIdx.x * 256 + threadIdx.x;
    const int n1 = RR * FIN * FHID;
    const int n2 = RR * FHID * FOUT;
    if (idx < n1) {
        int r = idx / (FIN * FHID);
        int rem = idx - r * FIN * FHID;
        int k = rem / FHID, m = rem - k * FHID;
        Wt1[((size_t)r * FHID + m) * FIN + k] = (unsigned short)bf16round(W1[idx]);
    } else if (idx - n1 < n2) {
        int j = idx - n1;
        int r = j / (FHID * FOUT);
        int rem = j - r * FHID * FOUT;
        int k = rem / FOUT, m = rem - k * FOUT;
        Wt2[((size_t)r * FOUT + m) * FHID + k] = (unsigned short)bf16round(W2[j]);
    }
}

// ---------------- LDS-histogram degree count (packed u16 counters) ----
// grid: 2(dir) x RR x NCHUNK_H x GH = 1200 blocks, 512 threads.
// cnt halves can't carry: per-slice per-node count <= SLICE = 10000 < 65536.
__global__ __launch_bounds__(512) void hist_deg_kernel(
    const int* __restrict__ src, const int* __restrict__ dst,
    unsigned short* __restrict__ partial_in, unsigned short* __restrict__ partial_out)
{
    __shared__ unsigned cnt[CH_H / 2];   // 50 KB
    const int b   = blockIdx.x;
    const int dir = b / (RR * NCHUNK_H * GH);
    const int rem = b % (RR * NCHUNK_H * GH);
    const int r   = rem / (NCHUNK_H * GH);
    const int c   = (rem / GH) % NCHUNK_H;
    const int g   = rem % GH;
    const int tid = threadIdx.x;

    for (int i = tid; i < CH_H / 2; i += 512) cnt[i] = 0;
    __syncthreads();

    const int* ids = (dir ? src : dst) + (size_t)r * EE + (size_t)g * SLICE;
    const int base = c * CH_H;
    for (int i4 = tid; i4 < SLICE / 4; i4 += 512) {
        int4 q = reinterpret_cast<const int4*>(ids)[i4];
        int d;
        d = q.x - base; if ((unsigned)d < (unsigned)CH_H) atomicAdd(&cnt[d >> 1], 1u << ((d & 1) * 16));
        d = q.y - base; if ((unsigned)d < (unsigned)CH_H) atomicAdd(&cnt[d >> 1], 1u << ((d & 1) * 16));
        d = q.z - base; if ((unsigned)d < (unsigned)CH_H) atomicAdd(&cnt[d >> 1], 1u << ((d & 1) * 16));
        d = q.w - base; if ((unsigned)d < (unsigned)CH_H) atomicAdd(&cnt[d >> 1], 1u << ((d & 1) * 16));
    }
    __syncthreads();

    unsigned short* part = (dir ? partial_out : partial_in)
                           + (size_t)g * RR * NN + (size_t)r * NN + base;
    for (int i = tid; i < CH_H; i += 512) {
        unsigned v = cnt[i >> 1];
        part[i] = (unsigned short)((v >> ((i & 1) * 16)) & 0xFFFFu);
    }
}

// reduce partials -> deg_in + s_in (dir 0) / s_out (dir 1)
__global__ __launch_bounds__(256) void reduce_deg_kernel(
    const unsigned short* __restrict__ partial_in,
    const unsigned short* __restrict__ partial_out,
    int* __restrict__ deg_in, float* __restrict__ s_in, float* __restrict__ s_out)
{
    int idx = blockIdx.x * 256 + threadIdx.x;
    if (idx >= 2 * RR * NN) return;
    int dir = idx / (RR * NN);
    int j   = idx % (RR * NN);
    const unsigned short* part = dir ? partial_out : partial_in;
    int s = 0;
    #pragma unroll
    for (int g = 0; g < GH; ++g) s += part[(size_t)g * RR * NN + j];
    float v = rsqrtf((float)max(s, 1));
    if (dir == 0) { deg_in[j] = s; s_in[j] = v; }
    else          { s_out[j] = v; }
}

// ---------------- scan over COMBINED degrees -> rp_c ----------------
__global__ __launch_bounds__(1024) void scan_reduce_kernel(
    const int* __restrict__ deg_in, int* __restrict__ bsum)
{
    const int b = blockIdx.x;
    const int t = threadIdx.x;
    int n0 = b * SCAN_TILE + t * 4;
    int s = 0;
    if (n0 + 3 < NN) {
        int4 a = *reinterpret_cast<const int4*>(&deg_in[n0]);
        int4 bq = *reinterpret_cast<const int4*>(&deg_in[NN + n0]);
        int4 cq = *reinterpret_cast<const int4*>(&deg_in[2 * NN + n0]);
        s = a.x + a.y + a.z + a.w + bq.x + bq.y + bq.z + bq.w + cq.x + cq.y + cq.z + cq.w;
    } else {
        for (int i = 0; i < 4; ++i)
            if (n0 + i < NN)
                s += deg_in[n0 + i] + deg_in[NN + n0 + i] + deg_in[2 * NN + n0 + i];
    }
    __shared__ int sh[1024];
    sh[t] = s;
    __syncthreads();
    for (int off = 512; off > 0; off >>= 1) {
        if (t < off) sh[t] += sh[t + off];
        __syncthreads();
    }
    if (t == 0) bsum[b] = sh[0];
}

__global__ void scan_spine_kernel(int* __restrict__ bsum)
{
    if (threadIdx.x != 0 || blockIdx.x != 0) return;
    int run = 0;
    for (int i = 0; i < NB; ++i) {
        int v = bsum[i];
        bsum[i] = run;
        run += v;
    }
}

__global__ __launch_bounds__(1024) void scan_final_kernel(
    const int* __restrict__ deg_in, const int* __restrict__ bsum,
    int* __restrict__ rp_c)
{
    const int b = blockIdx.x;
    const int t = threadIdx.x;
    int n0 = b * SCAN_TILE + t * 4;
    int v[4] = {0, 0, 0, 0};
    for (int i = 0; i < 4; ++i)
        if (n0 + i < NN)
            v[i] = deg_in[n0 + i] + deg_in[NN + n0 + i] + deg_in[2 * NN + n0 + i];
    int s = v[0] + v[1] + v[2] + v[3];
    __shared__ int sh[1024];
    sh[t] = s;
    __syncthreads();
    for (int off = 1; off < 1024; off <<= 1) {
        int x = (t >= off) ? sh[t - off] : 0;
        __syncthreads();
        if (t >= off) sh[t] += x;
        __syncthreads();
    }
    int off = bsum[b] + sh[t] - s;
    for (int i = 0; i < 4; ++i) {
        if (n0 + i < NN) { rp_c[n0 + i] = off; off += v[i]; }
    }
    if (b == NB - 1 && t == 0) rp_c[NN] = EEC;
}

// ---------------- combined slice bases: base_c[g][n] ----------------
__global__ __launch_bounds__(256) void slice_off_kernel(
    const int* __restrict__ rp_c, const unsigned short* __restrict__ partial_in,
    int* __restrict__ base_c)
{
    int n = blockIdx.x * 256 + threadIdx.x;
    if (n >= NN) return;
    int base = rp_c[n];
    #pragma unroll
    for (int g = 0; g < GH; ++g) {
        base_c[(size_t)g * NN + n] = base;
        const unsigned short* p = partial_in + (size_t)g * RR * NN + n;
        base += (int)p[0] + (int)p[NN] + (int)p[2 * NN];
    }
}

// ---------------- combined atomic-free CSR fill (1024 thr, int4 edges) ----------
// NCHUNK_F=8 (12500-node chunks, 50 KB LDS): 8 edge passes. grid 8x50 = 400.
__global__ __launch_bounds__(1024) void fill3_kernel(
    const int* __restrict__ src, const int* __restrict__ dst,
    const int* __restrict__ base_c, const float* __restrict__ s_in,
    uint2* __restrict__ col2)
{
    __shared__ int cur[CH_F];   // 50 KB
    const int b   = blockIdx.x;
    const int c   = b / GH;
    const int g   = b % GH;
    const int tid = threadIdx.x;
    const int base = c * CH_F;

    const int* so = base_c + (size_t)g * NN + base;
    for (int i = tid; i < CH_F; i += 1024) cur[i] = so[i];
    __syncthreads();

    for (int r = 0; r < RR; ++r) {
        const int* ds = dst + (size_t)r * EE + (size_t)g * SLICE;
        const int* ss = src + (size_t)r * EE + (size_t)g * SLICE;
        const float* si = s_in + (size_t)r * NN;
        const unsigned rbase = (unsigned)(r * NN);
        for (int i4 = tid; i4 < SLICE / 4; i4 += 1024) {
            int4 d4 = reinterpret_cast<const int4*>(ds)[i4];
            int4 s4 = reinterpret_cast<const int4*>(ss)[i4];
            int dl;
            dl = d4.x - base;
            if ((unsigned)dl < (unsigned)CH_F) {
                int pos = atomicAdd(&cur[dl], 1);
                col2[pos] = make_uint2(rbase + (unsigned)s4.x, __float_as_uint(si[d4.x]));
            }
            dl = d4.y - base;
            if ((unsigned)dl < (unsigned)CH_F) {
                int pos = atomicAdd(&cur[dl], 1);
                col2[pos] = make_uint2(rbase + (unsigned)s4.y, __float_as_uint(si[d4.y]));
            }
            dl = d4.z - base;
            if ((unsigned)dl < (unsigned)CH_F) {
                int pos = atomicAdd(&cur[dl], 1);
                col2[pos] = make_uint2(rbase + (unsigned)s4.z, __float_as_uint(si[d4.z]));
            }
            dl = d4.w - base;
            if ((unsigned)dl < (unsigned)CH_F) {
                int pos = atomicAdd(&cur[dl], 1);
                col2[pos] = make_uint2(rbase + (unsigned)s4.w, __float_as_uint(si[d4.w]));
            }
        }
    }
}

// ---------------- GEMM v6: BM=64, BN=64, BK=64, 2x2 waves ----------------
template<int K, int CN, bool A_F32>
__global__ __launch_bounds__(256) void gemm_v6_kernel(
    const void* __restrict__ Av, const unsigned short* __restrict__ Wt_base,
    const float* __restrict__ srow_base, unsigned short* __restrict__ C_base, int N)
{
    constexpr int BM  = 64;
    constexpr int BK  = 64;
    constexpr int MF  = 2;
    constexpr int NF  = 2;
    constexpr int LDA = A_F32 ? (BK + 8) : BK;

    __shared__ unsigned short As[BM * LDA];      // 9.2 / 8 KB
    __shared__ unsigned short Bs[RR][64 * BK];   // 24.5 KB
    __shared__ float sLds[RR][BM];               // 768 B

    const int tid  = threadIdx.x;
    const int wave = tid >> 6;
    const int lane = tid & 63;
    const int wr   = wave >> 1;
    const int wc   = wave & 1;
    const int row0 = blockIdx.x * BM;
    const int bh   = blockIdx.y;                 // 64-col half
    const int l15  = lane & 15;
    const int lq   = lane >> 4;

    for (int i = tid; i < RR * BM; i += 256) {
        int r  = i / BM;
        int rr = row0 + (i % BM);
        sLds[r][i % BM] = (rr < N) ? srow_base[(size_t)r * NN + rr] : 0.f;
    }

    f32x4 acc[RR][MF][NF];
    #pragma unroll
    for (int r = 0; r < RR; ++r)
        #pragma unroll
        for (int mi = 0; mi < MF; ++mi)
            #pragma unroll
            for (int ni = 0; ni < NF; ++ni)
                #pragma unroll
                for (int q = 0; q < 4; ++q) acc[r][mi][ni][q] = 0.0f;

    for (int k0 = 0; k0 < K; k0 += BK) {
        __syncthreads();
        // ---- stage A tile (64 rows x 64 k) ----
        if constexpr (A_F32) {
            const float* A = (const float*)Av;
            #pragma unroll
            for (int i = 0; i < 2; ++i) {
                int c2  = i * 256 + tid;       // 0..511
                int row = c2 >> 3;
                int fc  = (c2 & 7) * 2;
                float4 v0 = make_float4(0.f, 0.f, 0.f, 0.f);
                float4 v1 = make_float4(0.f, 0.f, 0.f, 0.f);
                if (row0 + row < N) {
                    const float* Ar = A + (size_t)(row0 + row) * K + k0 + fc * 4;
                    v0 = *reinterpret_cast<const float4*>(Ar);
                    v1 = *reinterpret_cast<const float4*>(Ar + 4);
                }
                uint4 o;
                o.x = pack2_bf16(v0.x, v0.y);
                o.y = pack2_bf16(v0.z, v0.w);
                o.z = pack2_bf16(v1.x, v1.y);
                o.w = pack2_bf16(v1.z, v1.w);
                *reinterpret_cast<uint4*>(&As[row * LDA + fc * 4]) = o;
            }
        } else {
            const unsigned short* A = (const unsigned short*)Av;
            #pragma unroll
            for (int i = 0; i < 2; ++i) {
                int c   = i * 256 + tid;       // 0..511
                int row = c >> 3;
                int kc  = c & 7;
                int kcs = kc ^ (row & 7);
                if (row0 + row < N)
                    gload_lds16(A + (size_t)(row0 + row) * K + k0 + kcs * 8, &As[c * 8]);
            }
        }
        // ---- stage B tiles (3 relations x 64 n x 64 k) ----
        #pragma unroll
        for (int i = 0; i < 6; ++i) {
            int c  = i * 256 + tid;        // 0..1535
            int r  = c >> 9;
            int cc = c & 511;
            int n  = cc >> 3;
            int kc = cc & 7;
            int kcs = kc ^ (n & 7);
            gload_lds16(Wt_base + ((size_t)r * CN + bh * 64 + n) * K + k0 + kcs * 8,
                        &Bs[r][cc * 8]);
        }
        __syncthreads();

        #pragma unroll
        for (int kk = 0; kk < BK; kk += 32) {
            const int j = kk / 8 + lq;
            bf16x8 af[MF];
            #pragma unroll
            for (int mi = 0; mi < MF; ++mi) {
                int row = wr * 32 + mi * 16 + l15;
                if constexpr (A_F32)
                    af[mi] = *reinterpret_cast<const bf16x8*>(&As[row * LDA + kk + lq * 8]);
                else
                    af[mi] = *reinterpret_cast<const bf16x8*>(&As[row * BK + (j ^ (row & 7)) * 8]);
            }
            #pragma unroll
            for (int r = 0; r < RR; ++r) {
                bf16x8 bfg[NF];
                #pragma unroll
                for (int ni = 0; ni < NF; ++ni) {
                    int n = wc * 32 + ni * 16 + l15;
                    bfg[ni] = *reinterpret_cast<const bf16x8*>(&Bs[r][n * BK + (j ^ (n & 7)) * 8]);
                }
                #pragma unroll
                for (int mi = 0; mi < MF; ++mi)
                    #pragma unroll
                    for (int ni = 0; ni < NF; ++ni)
                        acc[r][mi][ni] = __builtin_amdgcn_mfma_f32_16x16x32_bf16(
                            af[mi], bfg[ni], acc[r][mi][ni], 0, 0, 0);
            }
        }
    }

    // ---- epilogue: scale rows by s_out_r, write C (bf16) ----
    #pragma unroll
    for (int r = 0; r < RR; ++r) {
        unsigned short* C = C_base + (size_t)r * NN * CN;
        #pragma unroll
        for (int mi = 0; mi < MF; ++mi) {
            int lrow = wr * 32 + mi * 16 + lq * 4;
            #pragma unroll
            for (int ni = 0; ni < NF; ++ni) {
                int cc = bh * 64 + wc * 32 + ni * 16 + l15;
                #pragma unroll
                for (int q = 0; q < 4; ++q) {
                    int rr = row0 + lrow + q;
                    if (rr < N)
                        C[(size_t)rr * CN + cc] =
                            (unsigned short)bf16round(acc[r][mi][ni][q] * sLds[r][lrow + q]);
                }
            }
        }
    }
}

// ---------------- gather layer 1 (flat CSR, 8/4/1 ILP): h1(bf16) ----------------
__global__ __launch_bounds__(256) void gather1_kernel(
    const unsigned* __restrict__ Y, const uint2* __restrict__ col2,
    const int* __restrict__ rp_c, const float* __restrict__ b1,
    unsigned* __restrict__ h1)
{
    const int wid  = threadIdx.x >> 6;
    const int lane = threadIdx.x & 63;
    const int n    = blockIdx.x * 4 + wid;
    if (n >= NN) return;
    const int beg = rp_c[n], end = rp_c[n + 1];

    float ax[8], ay[8];
    #pragma unroll
    for (int j = 0; j < 8; ++j) { ax[j] = 0.f; ay[j] = 0.f; }

    int e = beg;
    for (; e + 7 < end; e += 8) {
        uint2 cc[8]; unsigned uu[8];
        #pragma unroll
        for (int j = 0; j < 8; ++j) cc[j] = col2[e + j];
        #pragma unroll
        for (int j = 0; j < 8; ++j) uu[j] = Y[(size_t)cc[j].x * 64 + lane];
        #pragma unroll
        for (int j = 0; j < 8; ++j) {
            float s = __uint_as_float(cc[j].y);
            ax[j] = fmaf(s, bflo(uu[j]), ax[j]);
            ay[j] = fmaf(s, bfhi(uu[j]), ay[j]);
        }
    }
    for (; e + 3 < end; e += 4) {
        uint2 cc[4]; unsigned uu[4];
        #pragma unroll
        for (int j = 0; j < 4; ++j) cc[j] = col2[e + j];
        #pragma unroll
        for (int j = 0; j < 4; ++j) uu[j] = Y[(size_t)cc[j].x * 64 + lane];
        #pragma unroll
        for (int j = 0; j < 4; ++j) {
            float s = __uint_as_float(cc[j].y);
            ax[j] = fmaf(s, bflo(uu[j]), ax[j]);
            ay[j] = fmaf(s, bfhi(uu[j]), ay[j]);
        }
    }
    for (; e < end; ++e) {
        uint2 c0 = col2[e];
        unsigned u0 = Y[(size_t)c0.x * 64 + lane];
        float s = __uint_as_float(c0.y);
        ax[0] = fmaf(s, bflo(u0), ax[0]);
        ay[0] = fmaf(s, bfhi(u0), ay[0]);
    }
    float sx = ((ax[0] + ax[1]) + (ax[2] + ax[3])) + ((ax[4] + ax[5]) + (ax[6] + ax[7]));
    float sy = ((ay[0] + ay[1]) + (ay[2] + ay[3])) + ((ay[4] + ay[5]) + (ay[6] + ay[7]));
    float bx = b1[lane * 2]     + b1[FHID + lane * 2]     + b1[2 * FHID + lane * 2];
    float by = b1[lane * 2 + 1] + b1[FHID + lane * 2 + 1] + b1[2 * FHID + lane * 2 + 1];
    const float inv = 1.0f / (float)RR;
    float ox = fmaxf((sx + bx) * inv, 0.f);
    float oy = fmaxf((sy + by) * inv, 0.f);
    h1[(size_t)n * 64 + lane] = pack2_bf16(ox, oy);
}

// ---------------- gather layer 2 (flat CSR, 8/4/1 ILP): h2(bf16) ----------------
__global__ __launch_bounds__(256) void gather2_kernel(
    const unsigned short* __restrict__ Y, const uint2* __restrict__ col2,
    const int* __restrict__ rp_c, const float* __restrict__ b2,
    unsigned short* __restrict__ h2)
{
    const int wid  = threadIdx.x >> 6;
    const int lane = threadIdx.x & 63;
    const int n    = blockIdx.x * 4 + wid;
    if (n >= NN) return;
    const int beg = rp_c[n], end = rp_c[n + 1];

    float a[8];
    #pragma unroll
    for (int j = 0; j < 8; ++j) a[j] = 0.f;

    int e = beg;
    for (; e + 7 < end; e += 8) {
        uint2 cc[8]; unsigned short uu[8];
        #pragma unroll
        for (int j = 0; j < 8; ++j) cc[j] = col2[e + j];
        #pragma unroll
        for (int j = 0; j < 8; ++j) uu[j] = Y[(size_t)cc[j].x * 64 + lane];
        #pragma unroll
        for (int j = 0; j < 8; ++j)
            a[j] = fmaf(__uint_as_float(cc[j].y),
                        __uint_as_float((unsigned)uu[j] << 16), a[j]);
    }
    for (; e + 3 < end; e += 4) {
        uint2 cc[4]; unsigned short uu[4];
        #pragma unroll
        for (int j = 0; j < 4; ++j) cc[j] = col2[e + j];
        #pragma unroll
        for (int j = 0; j < 4; ++j) uu[j] = Y[(size_t)cc[j].x * 64 + lane];
        #pragma unroll
        for (int j = 0; j < 4; ++j)
            a[j] = fmaf(__uint_as_float(cc[j].y),
                        __uint_as_float((unsigned)uu[j] << 16), a[j]);
    }
    for (; e < end; ++e) {
        uint2 c0 = col2[e];
        a[0] = fmaf(__uint_as_float(c0.y),
                    __uint_as_float((unsigned)Y[(size_t)c0.x * 64 + lane] << 16), a[0]);
    }
    float s = ((a[0] + a[1]) + (a[2] + a[3])) + ((a[4] + a[5]) + (a[6] + a[7]));
    float bs = b2[lane] + b2[FOUT + lane] + b2[2 * FOUT + lane];
    float o = (s + bs) * (1.0f / (float)RR);
    h2[(size_t)n * 64 + lane] = (unsigned short)bf16round(o);
}

// ---------------- edge dot-product scores (bf16 h2, 8 lanes/edge, uint4) ----------
__global__ __launch_bounds__(256) void score_kernel(
    const unsigned short* __restrict__ h, const int* __restrict__ src0,
    const int* __restrict__ dst0, const int* __restrict__ nsrc,
    const int* __restrict__ ndst, float* __restrict__ out)
{
    int idx = blockIdx.x * 256 + threadIdx.x;  // grid exact: 2*E*8
    int e = idx >> 3;
    int l = idx & 7;
    int u, v;
    if (e < EE) { u = src0[e]; v = dst0[e]; }
    else        { u = nsrc[e - EE]; v = ndst[e - EE]; }
    uint4 a = *reinterpret_cast<const uint4*>(&h[(size_t)u * FOUT + l * 8]);
    uint4 b = *reinterpret_cast<const uint4*>(&h[(size_t)v * FOUT + l * 8]);
    float p = bflo(a.x) * bflo(b.x) + bfhi(a.x) * bfhi(b.x)
            + bflo(a.y) * bflo(b.y) + bfhi(a.y) * bfhi(b.y)
            + bflo(a.z) * bflo(b.z) + bfhi(a.z) * bfhi(b.z)
            + bflo(a.w) * bflo(b.w) + bfhi(a.w) * bfhi(b.w);
    p += __shfl_xor(p, 4, 8);
    p += __shfl_xor(p, 2, 8);
    p += __shfl_xor(p, 1, 8);
    if (l == 0) out[e] = p;
}

// ---------------- launch ----------------
extern "C" void kernel_launch(void* const* d_in, const int* in_sizes, int n_in,
                              void* d_out, int out_size, void* d_ws, size_t ws_size,
                              hipStream_t stream)
{
    const float* feature = (const float*)d_in[0];
    const float* W1      = (const float*)d_in[1];
    const float* b1      = (const float*)d_in[2];
    const float* W2      = (const float*)d_in[3];
    const float* b2      = (const float*)d_in[4];
    const int*   src     = (const int*)d_in[5];
    const int*   dst     = (const int*)d_in[6];
    const int*   nsrc    = (const int*)d_in[7];
    const int*   ndst    = (const int*)d_in[8];
    float* out = (float*)d_out;

    // workspace (~132 MB); Yu union: ushort partials (30+30 MB) + base_c -> Y1/Y2
    char* p = (char*)d_ws;
    float* s_out   = (float*)p; p += sizeof(float) * RR * NN;
    float* s_in    = (float*)p; p += sizeof(float) * RR * NN;
    unsigned* h1   = (unsigned*)p; p += sizeof(unsigned) * (size_t)NN * 64;   // bf16x2
    unsigned short* h2 = (unsigned short*)p; p += sizeof(unsigned short) * (size_t)NN * FOUT;
    char*  Yu      = p;         p += (size_t)RR * NN * FHID * 2;              // 76.8 MB union
    int*   deg_in  = (int*)p;   p += sizeof(int) * RR * NN;
    int*   rp_c    = (int*)p;   p += sizeof(int) * (NN + 1);
    uint2* col2    = (uint2*)p; p += sizeof(uint2) * (size_t)EEC;             // 12 MB
    int*   bsum    = (int*)p;   p += sizeof(int) * NB;
    unsigned short* Wt1 = (unsigned short*)p; p += sizeof(unsigned short) * RR * FIN * FHID;
    unsigned short* Wt2 = (unsigned short*)p; p += sizeof(unsigned short) * RR * FHID * FOUT;

    unsigned short* Y1 = (unsigned short*)Yu;                      // R x N x 128 bf16
    unsigned short* Y2 = (unsigned short*)Yu;                      // R x N x 64 bf16
    unsigned short* partial_in  = (unsigned short*)Yu;             // GH x R x N u16 (30 MB)
    unsigned short* partial_out = partial_in + (size_t)GH * RR * NN; // 30 MB
    int* base_c = (int*)partial_out;                               // GH x N int (20 MB, after reduce)

    // ---- prep + CSR build (no global atomics) ----
    convw_kernel<<<(RR * FIN * FHID + RR * FHID * FOUT + 255) / 256, 256, 0, stream>>>(
        W1, Wt1, W2, Wt2);
    hist_deg_kernel<<<2 * RR * NCHUNK_H * GH, 512, 0, stream>>>(
        src, dst, partial_in, partial_out);
    reduce_deg_kernel<<<(2 * RR * NN + 255) / 256, 256, 0, stream>>>(
        partial_in, partial_out, deg_in, s_in, s_out);
    scan_reduce_kernel<<<NB, 1024, 0, stream>>>(deg_in, bsum);
    scan_spine_kernel<<<1, 64, 0, stream>>>(bsum);
    scan_final_kernel<<<NB, 1024, 0, stream>>>(deg_in, bsum, rp_c);
    slice_off_kernel<<<(NN + 255) / 256, 256, 0, stream>>>(rp_c, partial_in, base_c);
    fill3_kernel<<<NCHUNK_F * GH, 1024, 0, stream>>>(src, dst, base_c, s_in, col2);

    const int node_grid = (NN + 3) / 4;
    const int gemm_gx = (NN + 63) / 64;

    // ---- layer 1: Y1_r = bf16(diag(s_out_r)*feature @ W1_r); h1 = relu(mean) ----
    gemm_v6_kernel<FIN, FHID, true><<<dim3(gemm_gx, 2), 256, 0, stream>>>(
        feature, Wt1, s_out, Y1, NN);
    gather1_kernel<<<node_grid, 256, 0, stream>>>(
        (const unsigned*)Y1, col2, rp_c, b1, h1);

    // ---- layer 2: Y2_r = bf16(diag(s_out_r)*h1 @ W2_r); h2 = mean ----
    gemm_v6_kernel<FHID, FOUT, false><<<dim3(gemm_gx, 1), 256, 0, stream>>>(
        h1, Wt2, s_out, Y2, NN);
    gather2_kernel<<<node_grid, 256, 0, stream>>>(
        Y2, col2, rp_c, b2, h2);

    // ---- scores ----
    score_kernel<<<(2 * EE * 8) / 256, 256, 0, stream>>>(h2, src, dst, nsrc, ndst, out);
}

// Round 25
// 329.597 us; speedup vs baseline: 1.0422x; 1.0008x over previous
//
#include <hip/hip_runtime.h>

// ---- problem constants (match reference) ----
namespace {
constexpr int NN   = 100000;  // nodes
constexpr int RR   = 3;       // relations
constexpr int EE   = 500000;  // edges per relation
constexpr int FIN  = 256;
constexpr int FHID = 128;
constexpr int FOUT = 64;
constexpr int EEC  = RR * EE;                         // combined edges
constexpr int SCAN_TILE = 4096;                       // elems per scan block
constexpr int NB = (NN + SCAN_TILE - 1) / SCAN_TILE;  // 25 blocks (combined scan)
// histogram geometry: packed u16 counters (counts <= SLICE < 65536), 25000-node
// chunks in 50 KB LDS -> 4 edge passes
constexpr int NCHUNK_H = 4;
constexpr int CH_H     = NN / NCHUNK_H;    // 25000
constexpr int GH       = 50;               // edge slices; SLICE*4B is 16B-aligned
constexpr int SLICE    = EE / GH;          // 10000
// fill geometry (12500-node chunks, 50 KB LDS, 1024 thr, grid 400; 8 passes)
constexpr int NCHUNK_F = 8;
constexpr int CH_F     = NN / NCHUNK_F;    // 12500
}

typedef float f32x4  __attribute__((ext_vector_type(4)));
typedef short bf16x8 __attribute__((ext_vector_type(8)));

__device__ inline unsigned bf16round(float a) {
    unsigned u = __float_as_uint(a);
    return (u + 0x7FFFu + ((u >> 16) & 1u)) >> 16;   // RNE
}
__device__ inline unsigned pack2_bf16(float a, float b) {
    return bf16round(a) | (bf16round(b) << 16);
}
__device__ inline float bflo(unsigned u) { return __uint_as_float(u << 16); }
__device__ inline float bfhi(unsigned u) { return __uint_as_float(u & 0xFFFF0000u); }

// async global->LDS 16B copy (linear dest: wave base + lane*16)
__device__ inline void gload_lds16(const unsigned short* g, unsigned short* l) {
    __builtin_amdgcn_global_load_lds(
        (const __attribute__((address_space(1))) void*)g,
        (__attribute__((address_space(3))) void*)l, 16, 0, 0);
}

// ---------------- fused weight transpose+convert: Wt[r][m][k] = bf16(W[r][k][m]) ----
__global__ __launch_bounds__(256) void convw_kernel(
    const float* __restrict__ W1, unsigned short* __restrict__ Wt1,
    const float* __restrict__ W2, unsigned short* __restrict__ Wt2)
{
    int idx = blockIdx.x * 256 + threadIdx.x;
    const int n1 = RR * FIN * FHID;
    const int n2 = RR * FHID * FOUT;
    if (idx < n1) {
        int r = idx / (FIN * FHID);
        int rem = idx - r * FIN * FHID;
        int k = rem / FHID, m = rem - k * FHID;
        Wt1[((size_t)r * FHID + m) * FIN + k] = (unsigned short)bf16round(W1[idx]);
    } else if (idx - n1 < n2) {
        int j = idx - n1;
        int r = j / (FHID * FOUT);
        int rem = j - r * FHID * FOUT;
        int k = rem / FOUT, m = rem - k * FOUT;
        Wt2[((size_t)r * FOUT + m) * FHID + k] = (unsigned short)bf16round(W2[j]);
    }
}

// ---------------- LDS-histogram degree count (packed u16 counters) ----
// grid: 2(dir) x RR x NCHUNK_H x GH = 1200 blocks, 512 threads.
__global__ __launch_bounds__(512) void hist_deg_kernel(
    const int* __restrict__ src, const int* __restrict__ dst,
    unsigned short* __restrict__ partial_in, unsigned short* __restrict__ partial_out)
{
    __shared__ unsigned cnt[CH_H / 2];   // 50 KB
    const int b   = blockIdx.x;
    const int dir = b / (RR * NCHUNK_H * GH);
    const int rem = b % (RR * NCHUNK_H * GH);
    const int r   = rem / (NCHUNK_H * GH);
    const int c   = (rem / GH) % NCHUNK_H;
    const int g   = rem % GH;
    const int tid = threadIdx.x;

    for (int i = tid; i < CH_H / 2; i += 512) cnt[i] = 0;
    __syncthreads();

    const int* ids = (dir ? src : dst) + (size_t)r * EE + (size_t)g * SLICE;
    const int base = c * CH_H;
    for (int i4 = tid; i4 < SLICE / 4; i4 += 512) {
        int4 q = reinterpret_cast<const int4*>(ids)[i4];
        int d;
        d = q.x - base; if ((unsigned)d < (unsigned)CH_H) atomicAdd(&cnt[d >> 1], 1u << ((d & 1) * 16));
        d = q.y - base; if ((unsigned)d < (unsigned)CH_H) atomicAdd(&cnt[d >> 1], 1u << ((d & 1) * 16));
        d = q.z - base; if ((unsigned)d < (unsigned)CH_H) atomicAdd(&cnt[d >> 1], 1u << ((d & 1) * 16));
        d = q.w - base; if ((unsigned)d < (unsigned)CH_H) atomicAdd(&cnt[d >> 1], 1u << ((d & 1) * 16));
    }
    __syncthreads();

    // flush: cnt[i] is already the packed (node base+2i, base+2i+1) pair
    unsigned* partw = (unsigned*)((dir ? partial_out : partial_in)
                      + (size_t)g * RR * NN + (size_t)r * NN + base);
    for (int i = tid; i < CH_H / 2; i += 512) partw[i] = cnt[i];
}

// reduce partials -> deg_in + s_in (dir 0) / s_out (dir 1); uint-pair reads
__global__ __launch_bounds__(256) void reduce_deg_kernel(
    const unsigned short* __restrict__ partial_in,
    const unsigned short* __restrict__ partial_out,
    int* __restrict__ deg_in, float* __restrict__ s_in, float* __restrict__ s_out)
{
    constexpr int PAIRS = RR * NN / 2;
    int idx = blockIdx.x * 256 + threadIdx.x;   // pair index over both dirs
    if (idx >= 2 * PAIRS) return;
    int dir = idx / PAIRS;
    int jp  = idx % PAIRS;                      // pair: nodes j0=2*jp, j0+1 (never crosses r: NN even)
    const unsigned* part = (const unsigned*)(dir ? partial_out : partial_in);
    int s0 = 0, s1 = 0;
    #pragma unroll
    for (int g = 0; g < GH; ++g) {
        unsigned v = part[(size_t)g * PAIRS + jp];
        s0 += (int)(v & 0xFFFFu);
        s1 += (int)(v >> 16);
    }
    int j0 = jp * 2;
    float v0 = rsqrtf((float)max(s0, 1));
    float v1 = rsqrtf((float)max(s1, 1));
    if (dir == 0) {
        deg_in[j0] = s0; deg_in[j0 + 1] = s1;
        s_in[j0] = v0;   s_in[j0 + 1] = v1;
    } else {
        s_out[j0] = v0;  s_out[j0 + 1] = v1;
    }
}

// ---------------- scan over COMBINED degrees -> rp_c ----------------
__global__ __launch_bounds__(1024) void scan_reduce_kernel(
    const int* __restrict__ deg_in, int* __restrict__ bsum)
{
    const int b = blockIdx.x;
    const int t = threadIdx.x;
    int n0 = b * SCAN_TILE + t * 4;
    int s = 0;
    if (n0 + 3 < NN) {
        int4 a = *reinterpret_cast<const int4*>(&deg_in[n0]);
        int4 bq = *reinterpret_cast<const int4*>(&deg_in[NN + n0]);
        int4 cq = *reinterpret_cast<const int4*>(&deg_in[2 * NN + n0]);
        s = a.x + a.y + a.z + a.w + bq.x + bq.y + bq.z + bq.w + cq.x + cq.y + cq.z + cq.w;
    } else {
        for (int i = 0; i < 4; ++i)
            if (n0 + i < NN)
                s += deg_in[n0 + i] + deg_in[NN + n0 + i] + deg_in[2 * NN + n0 + i];
    }
    __shared__ int sh[1024];
    sh[t] = s;
    __syncthreads();
    for (int off = 512; off > 0; off >>= 1) {
        if (t < off) sh[t] += sh[t + off];
        __syncthreads();
    }
    if (t == 0) bsum[b] = sh[0];
}

// scan_final reads RAW bsum and computes the <=24-element prefix inline
__global__ __launch_bounds__(1024) void scan_final_kernel(
    const int* __restrict__ deg_in, const int* __restrict__ bsum,
    int* __restrict__ rp_c)
{
    const int b = blockIdx.x;
    const int t = threadIdx.x;
    int pre = 0;
    for (int i = 0; i < b; ++i) pre += bsum[i];   // uniform scalar loads (broadcast)
    int n0 = b * SCAN_TILE + t * 4;
    int v[4] = {0, 0, 0, 0};
    for (int i = 0; i < 4; ++i)
        if (n0 + i < NN)
            v[i] = deg_in[n0 + i] + deg_in[NN + n0 + i] + deg_in[2 * NN + n0 + i];
    int s = v[0] + v[1] + v[2] + v[3];
    __shared__ int sh[1024];
    sh[t] = s;
    __syncthreads();
    for (int off = 1; off < 1024; off <<= 1) {
        int x = (t >= off) ? sh[t - off] : 0;
        __syncthreads();
        if (t >= off) sh[t] += x;
        __syncthreads();
    }
    int off = pre + sh[t] - s;
    for (int i = 0; i < 4; ++i) {
        if (n0 + i < NN) { rp_c[n0 + i] = off; off += v[i]; }
    }
    if (b == NB - 1 && t == 0) rp_c[NN] = EEC;
}

// ---------------- combined slice bases: base_c[g][n] (uint-pair reads, int2 writes) ----
__global__ __launch_bounds__(256) void slice_off_kernel(
    const int* __restrict__ rp_c, const unsigned short* __restrict__ partial_in,
    int* __restrict__ base_c)
{
    int t = blockIdx.x * 256 + threadIdx.x;     // pair index
    if (t >= NN / 2) return;
    int n0 = 2 * t;
    int b0 = rp_c[n0], b1 = rp_c[n0 + 1];
    #pragma unroll
    for (int g = 0; g < GH; ++g) {
        *reinterpret_cast<int2*>(&base_c[(size_t)g * NN + n0]) = make_int2(b0, b1);
        const unsigned* p = (const unsigned*)(partial_in + (size_t)g * RR * NN);
        unsigned v0 = p[t];                 // r=0: nodes n0,n0+1
        unsigned v1 = p[(NN >> 1) + t];     // r=1
        unsigned v2 = p[NN + t];            // r=2
        b0 += (int)((v0 & 0xFFFFu) + (v1 & 0xFFFFu) + (v2 & 0xFFFFu));
        b1 += (int)((v0 >> 16) + (v1 >> 16) + (v2 >> 16));
    }
}

// ---------------- combined atomic-free CSR fill (1024 thr, int4 edges) ----------
__global__ __launch_bounds__(1024) void fill3_kernel(
    const int* __restrict__ src, const int* __restrict__ dst,
    const int* __restrict__ base_c, const float* __restrict__ s_in,
    uint2* __restrict__ col2)
{
    __shared__ int cur[CH_F];   // 50 KB
    const int b   = blockIdx.x;
    const int c   = b / GH;
    const int g   = b % GH;
    const int tid = threadIdx.x;
    const int base = c * CH_F;

    const int* so = base_c + (size_t)g * NN + base;
    for (int i = tid; i < CH_F; i += 1024) cur[i] = so[i];
    __syncthreads();

    for (int r = 0; r < RR; ++r) {
        const int* ds = dst + (size_t)r * EE + (size_t)g * SLICE;
        const int* ss = src + (size_t)r * EE + (size_t)g * SLICE;
        const float* si = s_in + (size_t)r * NN;
        const unsigned rbase = (unsigned)(r * NN);
        for (int i4 = tid; i4 < SLICE / 4; i4 += 1024) {
            int4 d4 = reinterpret_cast<const int4*>(ds)[i4];
            int4 s4 = reinterpret_cast<const int4*>(ss)[i4];
            int dl;
            dl = d4.x - base;
            if ((unsigned)dl < (unsigned)CH_F) {
                int pos = atomicAdd(&cur[dl], 1);
                col2[pos] = make_uint2(rbase + (unsigned)s4.x, __float_as_uint(si[d4.x]));
            }
            dl = d4.y - base;
            if ((unsigned)dl < (unsigned)CH_F) {
                int pos = atomicAdd(&cur[dl], 1);
                col2[pos] = make_uint2(rbase + (unsigned)s4.y, __float_as_uint(si[d4.y]));
            }
            dl = d4.z - base;
            if ((unsigned)dl < (unsigned)CH_F) {
                int pos = atomicAdd(&cur[dl], 1);
                col2[pos] = make_uint2(rbase + (unsigned)s4.z, __float_as_uint(si[d4.z]));
            }
            dl = d4.w - base;
            if ((unsigned)dl < (unsigned)CH_F) {
                int pos = atomicAdd(&cur[dl], 1);
                col2[pos] = make_uint2(rbase + (unsigned)s4.w, __float_as_uint(si[d4.w]));
            }
        }
    }
}

// ---------------- GEMM v6: BM=64, BN=64, BK=64, 2x2 waves ----------------
template<int K, int CN, bool A_F32>
__global__ __launch_bounds__(256) void gemm_v6_kernel(
    const void* __restrict__ Av, const unsigned short* __restrict__ Wt_base,
    const float* __restrict__ srow_base, unsigned short* __restrict__ C_base, int N)
{
    constexpr int BM  = 64;
    constexpr int BK  = 64;
    constexpr int MF  = 2;
    constexpr int NF  = 2;
    constexpr int LDA = A_F32 ? (BK + 8) : BK;

    __shared__ unsigned short As[BM * LDA];      // 9.2 / 8 KB
    __shared__ unsigned short Bs[RR][64 * BK];   // 24.5 KB
    __shared__ float sLds[RR][BM];               // 768 B

    const int tid  = threadIdx.x;
    const int wave = tid >> 6;
    const int lane = tid & 63;
    const int wr   = wave >> 1;
    const int wc   = wave & 1;
    const int row0 = blockIdx.x * BM;
    const int bh   = blockIdx.y;                 // 64-col half
    const int l15  = lane & 15;
    const int lq   = lane >> 4;

    for (int i = tid; i < RR * BM; i += 256) {
        int r  = i / BM;
        int rr = row0 + (i % BM);
        sLds[r][i % BM] = (rr < N) ? srow_base[(size_t)r * NN + rr] : 0.f;
    }

    f32x4 acc[RR][MF][NF];
    #pragma unroll
    for (int r = 0; r < RR; ++r)
        #pragma unroll
        for (int mi = 0; mi < MF; ++mi)
            #pragma unroll
            for (int ni = 0; ni < NF; ++ni)
                #pragma unroll
                for (int q = 0; q < 4; ++q) acc[r][mi][ni][q] = 0.0f;

    for (int k0 = 0; k0 < K; k0 += BK) {
        __syncthreads();
        // ---- stage A tile (64 rows x 64 k) ----
        if constexpr (A_F32) {
            const float* A = (const float*)Av;
            #pragma unroll
            for (int i = 0; i < 2; ++i) {
                int c2  = i * 256 + tid;       // 0..511
                int row = c2 >> 3;
                int fc  = (c2 & 7) * 2;
                float4 v0 = make_float4(0.f, 0.f, 0.f, 0.f);
                float4 v1 = make_float4(0.f, 0.f, 0.f, 0.f);
                if (row0 + row < N) {
                    const float* Ar = A + (size_t)(row0 + row) * K + k0 + fc * 4;
                    v0 = *reinterpret_cast<const float4*>(Ar);
                    v1 = *reinterpret_cast<const float4*>(Ar + 4);
                }
                uint4 o;
                o.x = pack2_bf16(v0.x, v0.y);
                o.y = pack2_bf16(v0.z, v0.w);
                o.z = pack2_bf16(v1.x, v1.y);
                o.w = pack2_bf16(v1.z, v1.w);
                *reinterpret_cast<uint4*>(&As[row * LDA + fc * 4]) = o;
            }
        } else {
            const unsigned short* A = (const unsigned short*)Av;
            #pragma unroll
            for (int i = 0; i < 2; ++i) {
                int c   = i * 256 + tid;       // 0..511
                int row = c >> 3;
                int kc  = c & 7;
                int kcs = kc ^ (row & 7);
                if (row0 + row < N)
                    gload_lds16(A + (size_t)(row0 + row) * K + k0 + kcs * 8, &As[c * 8]);
            }
        }
        // ---- stage B tiles (3 relations x 64 n x 64 k) ----
        #pragma unroll
        for (int i = 0; i < 6; ++i) {
            int c  = i * 256 + tid;        // 0..1535
            int r  = c >> 9;
            int cc = c & 511;
            int n  = cc >> 3;
            int kc = cc & 7;
            int kcs = kc ^ (n & 7);
            gload_lds16(Wt_base + ((size_t)r * CN + bh * 64 + n) * K + k0 + kcs * 8,
                        &Bs[r][cc * 8]);
        }
        __syncthreads();

        #pragma unroll
        for (int kk = 0; kk < BK; kk += 32) {
            const int j = kk / 8 + lq;
            bf16x8 af[MF];
            #pragma unroll
            for (int mi = 0; mi < MF; ++mi) {
                int row = wr * 32 + mi * 16 + l15;
                if constexpr (A_F32)
                    af[mi] = *reinterpret_cast<const bf16x8*>(&As[row * LDA + kk + lq * 8]);
                else
                    af[mi] = *reinterpret_cast<const bf16x8*>(&As[row * BK + (j ^ (row & 7)) * 8]);
            }
            #pragma unroll
            for (int r = 0; r < RR; ++r) {
                bf16x8 bfg[NF];
                #pragma unroll
                for (int ni = 0; ni < NF; ++ni) {
                    int n = wc * 32 + ni * 16 + l15;
                    bfg[ni] = *reinterpret_cast<const bf16x8*>(&Bs[r][n * BK + (j ^ (n & 7)) * 8]);
                }
                #pragma unroll
                for (int mi = 0; mi < MF; ++mi)
                    #pragma unroll
                    for (int ni = 0; ni < NF; ++ni)
                        acc[r][mi][ni] = __builtin_amdgcn_mfma_f32_16x16x32_bf16(
                            af[mi], bfg[ni], acc[r][mi][ni], 0, 0, 0);
            }
        }
    }

    // ---- epilogue: scale rows by s_out_r, write C (bf16) ----
    #pragma unroll
    for (int r = 0; r < RR; ++r) {
        unsigned short* C = C_base + (size_t)r * NN * CN;
        #pragma unroll
        for (int mi = 0; mi < MF; ++mi) {
            int lrow = wr * 32 + mi * 16 + lq * 4;
            #pragma unroll
            for (int ni = 0; ni < NF; ++ni) {
                int cc = bh * 64 + wc * 32 + ni * 16 + l15;
                #pragma unroll
                for (int q = 0; q < 4; ++q) {
                    int rr = row0 + lrow + q;
                    if (rr < N)
                        C[(size_t)rr * CN + cc] =
                            (unsigned short)bf16round(acc[r][mi][ni][q] * sLds[r][lrow + q]);
                }
            }
        }
    }
}

// ---------------- gather layer 1 (flat CSR, 8/4/1 ILP): h1(bf16) ----------------
__global__ __launch_bounds__(256) void gather1_kernel(
    const unsigned* __restrict__ Y, const uint2* __restrict__ col2,
    const int* __restrict__ rp_c, const float* __restrict__ b1,
    unsigned* __restrict__ h1)
{
    const int wid  = threadIdx.x >> 6;
    const int lane = threadIdx.x & 63;
    const int n    = blockIdx.x * 4 + wid;
    if (n >= NN) return;
    const int beg = rp_c[n], end = rp_c[n + 1];

    float ax[8], ay[8];
    #pragma unroll
    for (int j = 0; j < 8; ++j) { ax[j] = 0.f; ay[j] = 0.f; }

    int e = beg;
    for (; e + 7 < end; e += 8) {
        uint2 cc[8]; unsigned uu[8];
        #pragma unroll
        for (int j = 0; j < 8; ++j) cc[j] = col2[e + j];
        #pragma unroll
        for (int j = 0; j < 8; ++j) uu[j] = Y[(size_t)cc[j].x * 64 + lane];
        #pragma unroll
        for (int j = 0; j < 8; ++j) {
            float s = __uint_as_float(cc[j].y);
            ax[j] = fmaf(s, bflo(uu[j]), ax[j]);
            ay[j] = fmaf(s, bfhi(uu[j]), ay[j]);
        }
    }
    for (; e + 3 < end; e += 4) {
        uint2 cc[4]; unsigned uu[4];
        #pragma unroll
        for (int j = 0; j < 4; ++j) cc[j] = col2[e + j];
        #pragma unroll
        for (int j = 0; j < 4; ++j) uu[j] = Y[(size_t)cc[j].x * 64 + lane];
        #pragma unroll
        for (int j = 0; j < 4; ++j) {
            float s = __uint_as_float(cc[j].y);
            ax[j] = fmaf(s, bflo(uu[j]), ax[j]);
            ay[j] = fmaf(s, bfhi(uu[j]), ay[j]);
        }
    }
    for (; e < end; ++e) {
        uint2 c0 = col2[e];
        unsigned u0 = Y[(size_t)c0.x * 64 + lane];
        float s = __uint_as_float(c0.y);
        ax[0] = fmaf(s, bflo(u0), ax[0]);
        ay[0] = fmaf(s, bfhi(u0), ay[0]);
    }
    float sx = ((ax[0] + ax[1]) + (ax[2] + ax[3])) + ((ax[4] + ax[5]) + (ax[6] + ax[7]));
    float sy = ((ay[0] + ay[1]) + (ay[2] + ay[3])) + ((ay[4] + ay[5]) + (ay[6] + ay[7]));
    float bx = b1[lane * 2]     + b1[FHID + lane * 2]     + b1[2 * FHID + lane * 2];
    float by = b1[lane * 2 + 1] + b1[FHID + lane * 2 + 1] + b1[2 * FHID + lane * 2 + 1];
    const float inv = 1.0f / (float)RR;
    float ox = fmaxf((sx + bx) * inv, 0.f);
    float oy = fmaxf((sy + by) * inv, 0.f);
    h1[(size_t)n * 64 + lane] = pack2_bf16(ox, oy);
}

// ---------------- gather layer 2 (flat CSR, 8/4/1 ILP): h2(bf16) ----------------
__global__ __launch_bounds__(256) void gather2_kernel(
    const unsigned short* __restrict__ Y, const uint2* __restrict__ col2,
    const int* __restrict__ rp_c, const float* __restrict__ b2,
    unsigned short* __restrict__ h2)
{
    const int wid  = threadIdx.x >> 6;
    const int lane = threadIdx.x & 63;
    const int n    = blockIdx.x * 4 + wid;
    if (n >= NN) return;
    const int beg = rp_c[n], end = rp_c[n + 1];

    float a[8];
    #pragma unroll
    for (int j = 0; j < 8; ++j) a[j] = 0.f;

    int e = beg;
    for (; e + 7 < end; e += 8) {
        uint2 cc[8]; unsigned short uu[8];
        #pragma unroll
        for (int j = 0; j < 8; ++j) cc[j] = col2[e + j];
        #pragma unroll
        for (int j = 0; j < 8; ++j) uu[j] = Y[(size_t)cc[j].x * 64 + lane];
        #pragma unroll
        for (int j = 0; j < 8; ++j)
            a[j] = fmaf(__uint_as_float(cc[j].y),
                        __uint_as_float((unsigned)uu[j] << 16), a[j]);
    }
    for (; e + 3 < end; e += 4) {
        uint2 cc[4]; unsigned short uu[4];
        #pragma unroll
        for (int j = 0; j < 4; ++j) cc[j] = col2[e + j];
        #pragma unroll
        for (int j = 0; j < 4; ++j) uu[j] = Y[(size_t)cc[j].x * 64 + lane];
        #pragma unroll
        for (int j = 0; j < 4; ++j)
            a[j] = fmaf(__uint_as_float(cc[j].y),
                        __uint_as_float((unsigned)uu[j] << 16), a[j]);
    }
    for (; e < end; ++e) {
        uint2 c0 = col2[e];
        a[0] = fmaf(__uint_as_float(c0.y),
                    __uint_as_float((unsigned)Y[(size_t)c0.x * 64 + lane] << 16), a[0]);
    }
    float s = ((a[0] + a[1]) + (a[2] + a[3])) + ((a[4] + a[5]) + (a[6] + a[7]));
    float bs = b2[lane] + b2[FOUT + lane] + b2[2 * FOUT + lane];
    float o = (s + bs) * (1.0f / (float)RR);
    h2[(size_t)n * 64 + lane] = (unsigned short)bf16round(o);
}

// ---------------- edge dot-product scores (bf16 h2, 8 lanes/edge, uint4) ----------
__global__ __launch_bounds__(256) void score_kernel(
    const unsigned short* __restrict__ h, const int* __restrict__ src0,
    const int* __restrict__ dst0, const int* __restrict__ nsrc,
    const int* __restrict__ ndst, float* __restrict__ out)
{
    int idx = blockIdx.x * 256 + threadIdx.x;  // grid exact: 2*E*8
    int e = idx >> 3;
    int l = idx & 7;
    int u, v;
    if (e < EE) { u = src0[e]; v = dst0[e]; }
    else        { u = nsrc[e - EE]; v = ndst[e - EE]; }
    uint4 a = *reinterpret_cast<const uint4*>(&h[(size_t)u * FOUT + l * 8]);
    uint4 b = *reinterpret_cast<const uint4*>(&h[(size_t)v * FOUT + l * 8]);
    float p = bflo(a.x) * bflo(b.x) + bfhi(a.x) * bfhi(b.x)
            + bflo(a.y) * bflo(b.y) + bfhi(a.y) * bfhi(b.y)
            + bflo(a.z) * bflo(b.z) + bfhi(a.z) * bfhi(b.z)
            + bflo(a.w) * bflo(b.w) + bfhi(a.w) * bfhi(b.w);
    p += __shfl_xor(p, 4, 8);
    p += __shfl_xor(p, 2, 8);
    p += __shfl_xor(p, 1, 8);
    if (l == 0) out[e] = p;
}

// ---------------- launch ----------------
extern "C" void kernel_launch(void* const* d_in, const int* in_sizes, int n_in,
                              void* d_out, int out_size, void* d_ws, size_t ws_size,
                              hipStream_t stream)
{
    const float* feature = (const float*)d_in[0];
    const float* W1      = (const float*)d_in[1];
    const float* b1      = (const float*)d_in[2];
    const float* W2      = (const float*)d_in[3];
    const float* b2      = (const float*)d_in[4];
    const int*   src     = (const int*)d_in[5];
    const int*   dst     = (const int*)d_in[6];
    const int*   nsrc    = (const int*)d_in[7];
    const int*   ndst    = (const int*)d_in[8];
    float* out = (float*)d_out;

    // workspace (~132 MB); Yu union: ushort partials (30+30 MB) + base_c -> Y1/Y2
    char* p = (char*)d_ws;
    float* s_out   = (float*)p; p += sizeof(float) * RR * NN;
    float* s_in    = (float*)p; p += sizeof(float) * RR * NN;
    unsigned* h1   = (unsigned*)p; p += sizeof(unsigned) * (size_t)NN * 64;   // bf16x2
    unsigned short* h2 = (unsigned short*)p; p += sizeof(unsigned short) * (size_t)NN * FOUT;
    char*  Yu      = p;         p += (size_t)RR * NN * FHID * 2;              // 76.8 MB union
    int*   deg_in  = (int*)p;   p += sizeof(int) * RR * NN;
    int*   rp_c    = (int*)p;   p += sizeof(int) * (NN + 1);
    uint2* col2    = (uint2*)p; p += sizeof(uint2) * (size_t)EEC;             // 12 MB
    int*   bsum    = (int*)p;   p += sizeof(int) * NB;
    unsigned short* Wt1 = (unsigned short*)p; p += sizeof(unsigned short) * RR * FIN * FHID;
    unsigned short* Wt2 = (unsigned short*)p; p += sizeof(unsigned short) * RR * FHID * FOUT;

    unsigned short* Y1 = (unsigned short*)Yu;                      // R x N x 128 bf16
    unsigned short* Y2 = (unsigned short*)Yu;                      // R x N x 64 bf16
    unsigned short* partial_in  = (unsigned short*)Yu;             // GH x R x N u16 (30 MB)
    unsigned short* partial_out = partial_in + (size_t)GH * RR * NN; // 30 MB
    int* base_c = (int*)partial_out;                               // GH x N int (20 MB, after reduce)

    // ---- prep + CSR build (no global atomics) ----
    convw_kernel<<<(RR * FIN * FHID + RR * FHID * FOUT + 255) / 256, 256, 0, stream>>>(
        W1, Wt1, W2, Wt2);
    hist_deg_kernel<<<2 * RR * NCHUNK_H * GH, 512, 0, stream>>>(
        src, dst, partial_in, partial_out);
    reduce_deg_kernel<<<(RR * NN + 255) / 256, 256, 0, stream>>>(
        partial_in, partial_out, deg_in, s_in, s_out);
    scan_reduce_kernel<<<NB, 1024, 0, stream>>>(deg_in, bsum);
    scan_final_kernel<<<NB, 1024, 0, stream>>>(deg_in, bsum, rp_c);
    slice_off_kernel<<<(NN / 2 + 255) / 256, 256, 0, stream>>>(rp_c, partial_in, base_c);
    fill3_kernel<<<NCHUNK_F * GH, 1024, 0, stream>>>(src, dst, base_c, s_in, col2);

    const int node_grid = (NN + 3) / 4;
    const int gemm_gx = (NN + 63) / 64;

    // ---- layer 1: Y1_r = bf16(diag(s_out_r)*feature @ W1_r); h1 = relu(mean) ----
    gemm_v6_kernel<FIN, FHID, true><<<dim3(gemm_gx, 2), 256, 0, stream>>>(
        feature, Wt1, s_out, Y1, NN);
    gather1_kernel<<<node_grid, 256, 0, stream>>>(
        (const unsigned*)Y1, col2, rp_c, b1, h1);

    // ---- layer 2: Y2_r = bf16(diag(s_out_r)*h1 @ W2_r); h2 = mean ----
    gemm_v6_kernel<FHID, FOUT, false><<<dim3(gemm_gx, 1), 256, 0, stream>>>(
        h1, Wt2, s_out, Y2, NN);
    gather2_kernel<<<node_grid, 256, 0, stream>>>(
        Y2, col2, rp_c, b2, h2);

    // ---- scores ----
    score_kernel<<<(2 * EE * 8) / 256, 256, 0, stream>>>(h2, src, dst, nsrc, ndst, out);
}